// Round 6
// baseline (831.809 us; speedup 1.0000x reference)
//
#include <hip/hip_runtime.h>
#include <hip/hip_bf16.h>

#define N_NODES 50000
#define N_EDGES 800000
#define F_IN 128
#define HC 256
#define HEADS 4
#define HID 64
#define N_GRAPHS 64
#define N_CLASSES 16

typedef __attribute__((ext_vector_type(8))) short bfrag;    // 8 bf16 (4 VGPRs)
typedef __attribute__((ext_vector_type(4))) float f32x4;    // MFMA accumulator

__device__ __forceinline__ float wave_sum(float v) {
    #pragma unroll
    for (int off = 32; off > 0; off >>= 1) v += __shfl_xor(v, off);
    return v;
}

__device__ __forceinline__ unsigned int pack_bf2(float a, float b) {
    unsigned int ua = __bfloat16_as_ushort(__float2bfloat16(a));
    unsigned int ub = __bfloat16_as_ushort(__float2bfloat16(b));
    return ua | (ub << 16);
}

__device__ __forceinline__ float bf_lo(unsigned int u) { return __uint_as_float(u << 16); }
__device__ __forceinline__ float bf_hi(unsigned int u) { return __uint_as_float(u & 0xffff0000u); }

// ---------------- small utility kernels ----------------

__global__ void zero_f32(float* __restrict__ p, int n) {
    int i = blockIdx.x * 256 + threadIdx.x;
    if (i < n) p[i] = 0.f;
}

__global__ void deg_init(int* __restrict__ deg, int n) {
    int i = blockIdx.x * 256 + threadIdx.x;
    if (i < n) deg[i] = 1;  // self-loop
}

__global__ void deg_count(const int* __restrict__ dst, int* __restrict__ deg, int E) {
    int e = blockIdx.x * 256 + threadIdx.x;
    if (e < E) atomicAdd(&deg[dst[e]], 1);
}

// single-block exclusive scan over n=50000 ints
__global__ __launch_bounds__(1024) void scan_kernel(const int* __restrict__ deg,
                                                    int* __restrict__ rowptr,
                                                    int* __restrict__ cursor, int n) {
    __shared__ int part[1024];
    int t = threadIdx.x;
    int chunk = (n + 1023) >> 10;
    int c0 = t * chunk, c1 = min(c0 + chunk, n);
    int s = 0;
    for (int i = c0; i < c1; ++i) s += deg[i];
    part[t] = s;
    __syncthreads();
    for (int off = 1; off < 1024; off <<= 1) {
        int u = (t >= off) ? part[t - off] : 0;
        __syncthreads();
        part[t] += u;
        __syncthreads();
    }
    int run = part[t] - s;  // exclusive prefix
    for (int i = c0; i < c1; ++i) {
        rowptr[i] = run; cursor[i] = run; run += deg[i];
    }
    if (t == 1023) rowptr[n] = part[1023];
}

__global__ void csr_fill(const int* __restrict__ src, const int* __restrict__ dst,
                         int* __restrict__ cursor, int* __restrict__ csr_src, int E, int N) {
    int e = blockIdx.x * 256 + threadIdx.x;
    if (e >= E + N) return;
    int s, d;
    if (e < E) { s = src[e]; d = dst[e]; } else { s = d = e - E; }
    int pos = atomicAdd(&cursor[d], 1);
    csr_src[pos] = s;
}

// elementwise f32 -> bf16 (weights), n multiple of 4
__global__ void convert_w(const float* __restrict__ W, __hip_bfloat16* __restrict__ Wb, int n) {
    int i4 = (blockIdx.x * 256 + threadIdx.x) * 4;
    if (i4 >= n) return;
    float4 v = *reinterpret_cast<const float4*>(W + i4);
    ushort4 o;
    o.x = __bfloat16_as_ushort(__float2bfloat16(v.x));
    o.y = __bfloat16_as_ushort(__float2bfloat16(v.y));
    o.z = __bfloat16_as_ushort(__float2bfloat16(v.z));
    o.w = __bfloat16_as_ushort(__float2bfloat16(v.w));
    *reinterpret_cast<ushort4*>(Wb + i4) = o;
}

// ---------------- FastKAN via MFMA ----------------
// 16 nodes/block, 256 threads (4 waves). Wave w owns output cols [64w,64w+64) = head w.
// Basis (LN -> RBF) staged in LDS as bf16 [16][K].
// Swizzle: phys = b ^ ((row&7)<<4) ^ (((b>>7)&1)<<4)  -- spreads BOTH the write
// pattern (lane-stride 32B) and the A-frag read pattern across all 8 bank slots.
template <int IN, bool XBF>
__global__ __launch_bounds__(256) void fastkan_mfma(
    const void* __restrict__ xin_v, const float* __restrict__ ln_g, const float* __restrict__ ln_b,
    const __hip_bfloat16* __restrict__ Wb, const float* __restrict__ att_s, const float* __restrict__ att_d,
    __hip_bfloat16* __restrict__ hout, float* __restrict__ as_out, float* __restrict__ ad_out, int nnodes)
{
    constexpr int K  = IN * 4;   // bf16 elements per basis row
    constexpr int RB = K * 2;    // row bytes (1024 or 2048)
    constexpr int DPL = IN / 64; // input dims per lane (2 or 4)
    __shared__ __align__(16) unsigned char bas[16 * RB];

    int t = threadIdx.x, lane = t & 63, w = t >> 6;
    int lc = lane & 15, lr = lane >> 4;
    int base = blockIdx.x * 16;

    // ---- basis phase: wave w fills rows 4w..4w+3 ----
    for (int j = 0; j < 4; ++j) {
        int r = w * 4 + j;
        int node = base + r;
        unsigned char* rowp = bas + r * RB;
        int swz = (r & 7) << 4;
        if (node < nnodes) {
            float xv[DPL];
            if constexpr (XBF) {
                const unsigned short* xs = (const unsigned short*)xin_v + (size_t)node * IN + DPL * lane;
                ushort4 u = *reinterpret_cast<const ushort4*>(xs);
                xv[0] = bf_lo((unsigned)u.x << 16 >> 16);  // = bfu(u.x)
                xv[0] = __uint_as_float((unsigned)u.x << 16);
                xv[1] = __uint_as_float((unsigned)u.y << 16);
                xv[2] = __uint_as_float((unsigned)u.z << 16);
                xv[3] = __uint_as_float((unsigned)u.w << 16);
            } else {
                const float* xr = (const float*)xin_v + (size_t)node * IN + DPL * lane;
                if constexpr (DPL == 2) {
                    float2 v2 = *reinterpret_cast<const float2*>(xr);
                    xv[0] = v2.x; xv[1] = v2.y;
                } else {
                    float4 v4 = *reinterpret_cast<const float4*>(xr);
                    xv[0] = v4.x; xv[1] = v4.y; xv[2] = v4.z; xv[3] = v4.w;
                }
            }
            float s = 0.f, sq = 0.f;
            #pragma unroll
            for (int i = 0; i < DPL; ++i) { s += xv[i]; sq += xv[i] * xv[i]; }
            s = wave_sum(s); sq = wave_sum(sq);
            float mean = s * (1.f / IN);
            float var  = sq * (1.f / IN) - mean * mean;
            float rs = rsqrtf(var + 1e-5f);
            unsigned int pk[DPL * 2];
            #pragma unroll
            for (int i = 0; i < DPL; ++i) {
                int d = DPL * lane + i;
                float v = (xv[i] - mean) * rs * ln_g[d] + ln_b[d];
                float t0 = (v + 2.f) * 0.75f;
                float t1 = (v + 2.f / 3.f) * 0.75f;
                float t2 = (v - 2.f / 3.f) * 0.75f;
                float t3 = (v - 2.f) * 0.75f;
                float e0 = __expf(-t0 * t0), e1 = __expf(-t1 * t1);
                float e2 = __expf(-t2 * t2), e3 = __expf(-t3 * t3);
                pk[2 * i]     = pack_bf2(e0, e1);
                pk[2 * i + 1] = pack_bf2(e2, e3);
            }
            #pragma unroll
            for (int q = 0; q < DPL / 2; ++q) {
                int b = lane * DPL * 8 + q * 16;
                int off = (b ^ swz) ^ (((b >> 7) & 1) << 4);
                uint4 u; u.x = pk[4 * q]; u.y = pk[4 * q + 1]; u.z = pk[4 * q + 2]; u.w = pk[4 * q + 3];
                *reinterpret_cast<uint4*>(rowp + off) = u;
            }
        } else {
            uint4 z{};
            #pragma unroll
            for (int q = 0; q < DPL / 2; ++q) {
                int b = lane * DPL * 8 + q * 16;
                int off = (b ^ swz) ^ (((b >> 7) & 1) << 4);
                *reinterpret_cast<uint4*>(rowp + off) = z;
            }
        }
    }
    __syncthreads();

    // ---- MFMA phase: rows 0-15 (= lc), wave w -> cols 64w..64w+63 ----
    f32x4 acc[4] = {};
    const unsigned char* ap = bas + lc * RB;
    int aswz = (lc & 7) << 4;
    const __hip_bfloat16* wbase = Wb + (size_t)(w * 64 + lc) * K + lr * 8;

    #pragma unroll 4
    for (int ks = 0; ks < K / 32; ++ks) {
        int boff = ks * 64 + lr * 16;
        int poff = (boff ^ aswz) ^ (((boff >> 7) & 1) << 4);
        bfrag a = *reinterpret_cast<const bfrag*>(ap + poff);
        #pragma unroll
        for (int nf = 0; nf < 4; ++nf) {
            bfrag b = *reinterpret_cast<const bfrag*>(wbase + (size_t)nf * 16 * K + ks * 32);
            acc[nf] = __builtin_amdgcn_mfma_f32_16x16x32_bf16(a, b, acc[nf], 0, 0, 0);
        }
    }

    // ---- epilogue: C/D layout col=lane&15, row=(lane>>4)*4+reg ----
    float asw[4], adw[4];
    #pragma unroll
    for (int nf = 0; nf < 4; ++nf) {
        asw[nf] = att_s[w * 64 + nf * 16 + lc];
        adw[nf] = att_d[w * 64 + nf * 16 + lc];
    }
    #pragma unroll
    for (int reg = 0; reg < 4; ++reg) {
        int node = base + lr * 4 + reg;
        bool ok = node < nnodes;
        float ps = 0.f, pd = 0.f;
        #pragma unroll
        for (int nf = 0; nf < 4; ++nf) {
            float v = acc[nf][reg];
            ps = fmaf(v, asw[nf], ps);
            pd = fmaf(v, adw[nf], pd);
            if (ok) hout[(size_t)node * 256 + w * 64 + nf * 16 + lc] = __float2bfloat16(v);
        }
        #pragma unroll
        for (int off = 8; off; off >>= 1) {
            ps += __shfl_xor(ps, off);
            pd += __shfl_xor(pd, off);
        }
        if (ok && lc == 0) {
            as_out[node * 4 + w] = ps;
            ad_out[node * 4 + w] = pd;
        }
    }
}

// ---------------- fused GAT aggregation ----------------
// Block per dst node; 4 waves split the edge list (stride-4 interleave).
// Lane owns 4 columns (uint2 = 8B gather per edge). Partials combined in LDS.
__global__ __launch_bounds__(256) void gat_agg(
    const int* __restrict__ rowptr, const int* __restrict__ csr_src,
    const float* __restrict__ as_, const float* __restrict__ ad_,
    const __hip_bfloat16* __restrict__ h, const float* __restrict__ bias,
    __hip_bfloat16* __restrict__ out)
{
    __shared__ float accs[4][256];
    __shared__ float ses[4][4];
    int d = blockIdx.x, t = threadIdx.x, w = t >> 6, lane = t & 63;
    int head = lane >> 4;                 // cols lane*4..lane*4+3 are in head lane>>4
    int r0 = rowptr[d], r1 = rowptr[d + 1];
    float adv = ad_[d * 4 + head];
    const unsigned char* hb = (const unsigned char*)h;
    size_t loff = (size_t)lane * 8;

    float a0 = 0.f, a1 = 0.f, a2 = 0.f, a3 = 0.f, se = 0.f;
    int r = r0 + w;
    for (; r + 8 <= r1; r += 8) {
        int s0 = csr_src[r], s1 = csr_src[r + 4];
        float v0 = as_[s0 * 4 + head], v1 = as_[s1 * 4 + head];
        uint2 h0 = *reinterpret_cast<const uint2*>(hb + (size_t)s0 * 512 + loff);
        uint2 h1 = *reinterpret_cast<const uint2*>(hb + (size_t)s1 * 512 + loff);
        float e0 = v0 + adv; e0 = e0 > 0.f ? e0 : 0.2f * e0; e0 = __expf(e0);
        float e1 = v1 + adv; e1 = e1 > 0.f ? e1 : 0.2f * e1; e1 = __expf(e1);
        a0 = fmaf(e0, bf_lo(h0.x), a0); a1 = fmaf(e0, bf_hi(h0.x), a1);
        a2 = fmaf(e0, bf_lo(h0.y), a2); a3 = fmaf(e0, bf_hi(h0.y), a3);
        a0 = fmaf(e1, bf_lo(h1.x), a0); a1 = fmaf(e1, bf_hi(h1.x), a1);
        a2 = fmaf(e1, bf_lo(h1.y), a2); a3 = fmaf(e1, bf_hi(h1.y), a3);
        se += e0 + e1;
    }
    for (; r < r1; r += 4) {
        int s0 = csr_src[r];
        float v0 = as_[s0 * 4 + head];
        uint2 h0 = *reinterpret_cast<const uint2*>(hb + (size_t)s0 * 512 + loff);
        float e0 = v0 + adv; e0 = e0 > 0.f ? e0 : 0.2f * e0; e0 = __expf(e0);
        a0 = fmaf(e0, bf_lo(h0.x), a0); a1 = fmaf(e0, bf_hi(h0.x), a1);
        a2 = fmaf(e0, bf_lo(h0.y), a2); a3 = fmaf(e0, bf_hi(h0.y), a3);
        se += e0;
    }

    float4 av; av.x = a0; av.y = a1; av.z = a2; av.w = a3;
    *reinterpret_cast<float4*>(&accs[w][lane * 4]) = av;
    if ((lane & 15) == 0) ses[w][head] = se;
    __syncthreads();

    // combine: thread t owns column t
    float tot = accs[0][t] + accs[1][t] + accs[2][t] + accs[3][t];
    int hh = t >> 6;
    float sed = ses[0][hh] + ses[1][hh] + ses[2][hh] + ses[3][hh];
    float val = tot / sed + bias[t];
    val = val / (1.f + __expf(-val));  // silu
    out[(size_t)d * 256 + t] = __float2bfloat16(val);
}

// segment-sum pooling over sorted batch: block = (graph g, row-quarter q).
__global__ __launch_bounds__(256) void pool_kernel(
    const __hip_bfloat16* __restrict__ xo, const int* __restrict__ batch,
    float* __restrict__ pooled, int N)
{
    int g = blockIdx.x >> 2, q = blockIdx.x & 3, t = threadIdx.x;
    int lo = 0, hi = N;
    while (lo < hi) { int m = (lo + hi) >> 1; if (batch[m] < g) lo = m + 1; else hi = m; }
    int start = lo;
    hi = N;
    while (lo < hi) { int m = (lo + hi) >> 1; if (batch[m] <= g) lo = m + 1; else hi = m; }
    int end = lo;
    const unsigned short* xu = (const unsigned short*)xo;
    float acc = 0.f;
    for (int r = start + q; r < end; r += 4)
        acc += bf_lo((unsigned)xu[(size_t)r * 256 + t] << 16 >> 16), acc -= 0.f,
        acc += 0.f;  // placeholder removed below
    // (rewritten cleanly)
    acc = 0.f;
    for (int r = start + q; r < end; r += 4)
        acc += __uint_as_float((unsigned)xu[(size_t)r * 256 + t] << 16);
    atomicAdd(&pooled[g * 256 + t], acc);
}

// readout: LN -> RBF -> [16] logits -> log_softmax, one block per graph
__global__ __launch_bounds__(256) void readout_kernel(
    const float* __restrict__ pooled, const float* __restrict__ ln_g, const float* __restrict__ ln_b,
    const float* __restrict__ Wr, float* __restrict__ out)
{
    __shared__ __align__(16) float bas[1024];
    __shared__ float red[8];
    __shared__ float part[16][17];
    int t = threadIdx.x, lane = t & 63, w = t >> 6;
    int g = blockIdx.x;
    float val = pooled[g * 256 + t];
    float s = wave_sum(val), sq = wave_sum(val * val);
    if (lane == 0) { red[w] = s; red[4 + w] = sq; }
    __syncthreads();
    float stot = red[0] + red[1] + red[2] + red[3];
    float sqtot = red[4] + red[5] + red[6] + red[7];
    float mean = stot * (1.f / 256), var = sqtot * (1.f / 256) - mean * mean;
    float rs = rsqrtf(var + 1e-5f);
    float v = (val - mean) * rs * ln_g[t] + ln_b[t];
    float t0 = (v + 2.f) * 0.75f;
    float t1 = (v + 2.f / 3.f) * 0.75f;
    float t2 = (v - 2.f / 3.f) * 0.75f;
    float t3 = (v - 2.f) * 0.75f;
    float4 e4;
    e4.x = __expf(-t0 * t0); e4.y = __expf(-t1 * t1);
    e4.z = __expf(-t2 * t2); e4.w = __expf(-t3 * t3);
    reinterpret_cast<float4*>(bas)[t] = e4;
    __syncthreads();
    int o = t & 15, slice = t >> 4;
    float p = 0.f;
    const float* wrow = Wr + o * 1024 + slice * 64;
    const float* brow = bas + slice * 64;
    #pragma unroll 8
    for (int kk = 0; kk < 64; ++kk) p = fmaf(brow[kk], wrow[kk], p);
    part[o][slice] = p;
    __syncthreads();
    if (t < 16) {
        float l = 0.f;
        #pragma unroll
        for (int s2 = 0; s2 < 16; ++s2) l += part[t][s2];
        float m = l;
        #pragma unroll
        for (int off = 8; off; off >>= 1) m = fmaxf(m, __shfl_xor(m, off));
        float ex = __expf(l - m);
        float ssum = ex;
        #pragma unroll
        for (int off = 8; off; off >>= 1) ssum += __shfl_xor(ssum, off);
        out[g * 16 + t] = l - m - logf(ssum);
    }
}

// ---------------- launch ----------------

extern "C" void kernel_launch(void* const* d_in, const int* in_sizes, int n_in,
                              void* d_out, int out_size, void* d_ws, size_t ws_size,
                              hipStream_t stream) {
    const float* x      = (const float*)d_in[0];
    const int*   edge   = (const int*)d_in[1];
    const int*   batch  = (const int*)d_in[2];
    const float* ln_g0  = (const float*)d_in[3];
    const float* ln_b0  = (const float*)d_in[4];
    const float* W0     = (const float*)d_in[5];
    const float* att_s0 = (const float*)d_in[6];
    const float* att_d0 = (const float*)d_in[7];
    const float* bias0  = (const float*)d_in[8];
    const float* ln_g1  = (const float*)d_in[9];
    const float* ln_b1  = (const float*)d_in[10];
    const float* W1     = (const float*)d_in[11];
    const float* att_s1 = (const float*)d_in[12];
    const float* att_d1 = (const float*)d_in[13];
    const float* bias1  = (const float*)d_in[14];
    const float* ln_gr  = (const float*)d_in[15];
    const float* ln_br  = (const float*)d_in[16];
    const float* Wr     = (const float*)d_in[17];
    float* outp = (float*)d_out;

    const int N = N_NODES, E = N_EDGES;
    const int* src = edge;
    const int* dst = edge + E;

    unsigned char* ws = (unsigned char*)d_ws;
    size_t off = 0;
    auto alloc = [&](size_t nbytes) {
        unsigned char* p = ws + off;
        off += (nbytes + 255) & ~(size_t)255;
        return (void*)p;
    };
    __hip_bfloat16* W0b   = (__hip_bfloat16*)alloc(256 * 512 * 2);
    __hip_bfloat16* W1b   = (__hip_bfloat16*)alloc(256 * 1024 * 2);
    __hip_bfloat16* h_bf  = (__hip_bfloat16*)alloc((size_t)N * 256 * 2);
    __hip_bfloat16* xmid  = (__hip_bfloat16*)alloc((size_t)N * 256 * 2);  // reused for layer-2 output
    float* as_    = (float*)alloc((size_t)N * 4 * 4);
    float* ad_    = (float*)alloc((size_t)N * 4 * 4);
    int*   rowptr = (int*)alloc((N + 1) * 4);
    int*   cursor = (int*)alloc(N * 4);
    int*   deg    = (int*)alloc(N * 4);
    int*   csr_src= (int*)alloc((size_t)(E + N) * 4);
    float* pooled = (float*)alloc(N_GRAPHS * 256 * 4);

    deg_init<<<(N + 255) / 256, 256, 0, stream>>>(deg, N);
    deg_count<<<(E + 255) / 256, 256, 0, stream>>>(dst, deg, E);
    convert_w<<<(256 * 512 / 4 + 255) / 256, 256, 0, stream>>>(W0, W0b, 256 * 512);
    convert_w<<<(256 * 1024 / 4 + 255) / 256, 256, 0, stream>>>(W1, W1b, 256 * 1024);
    scan_kernel<<<1, 1024, 0, stream>>>(deg, rowptr, cursor, N);
    csr_fill<<<(E + N + 255) / 256, 256, 0, stream>>>(src, dst, cursor, csr_src, E, N);

    // layer 0
    fastkan_mfma<128, false><<<(N + 15) / 16, 256, 0, stream>>>(x, ln_g0, ln_b0, W0b,
                                                                att_s0, att_d0, h_bf, as_, ad_, N);
    gat_agg<<<N, 256, 0, stream>>>(rowptr, csr_src, as_, ad_, h_bf, bias0, xmid);

    // layer 1
    fastkan_mfma<256, true><<<(N + 15) / 16, 256, 0, stream>>>(xmid, ln_g1, ln_b1, W1b,
                                                               att_s1, att_d1, h_bf, as_, ad_, N);
    gat_agg<<<N, 256, 0, stream>>>(rowptr, csr_src, as_, ad_, h_bf, bias1, xmid);

    // pooling (batch sorted -> segmented streaming sum) + readout
    zero_f32<<<(N_GRAPHS * 256 + 255) / 256, 256, 0, stream>>>(pooled, N_GRAPHS * 256);
    pool_kernel<<<N_GRAPHS * 4, 256, 0, stream>>>(xmid, batch, pooled, N);
    readout_kernel<<<N_GRAPHS, 256, 0, stream>>>(pooled, ln_gr, ln_br, Wr, outp);
}

// Round 7
// 715.429 us; speedup vs baseline: 1.1627x; 1.1627x over previous
//
#include <hip/hip_runtime.h>
#include <hip/hip_bf16.h>

#define N_NODES 50000
#define N_EDGES 800000
#define F_IN 128
#define HC 256
#define HEADS 4
#define HID 64
#define N_GRAPHS 64
#define N_CLASSES 16

typedef __attribute__((ext_vector_type(8))) short bfrag;    // 8 bf16 (4 VGPRs)
typedef __attribute__((ext_vector_type(4))) float f32x4;    // MFMA accumulator

__device__ __forceinline__ float wave_sum(float v) {
    #pragma unroll
    for (int off = 32; off > 0; off >>= 1) v += __shfl_xor(v, off);
    return v;
}

__device__ __forceinline__ unsigned int pack_bf2(float a, float b) {
    unsigned int ua = __bfloat16_as_ushort(__float2bfloat16(a));
    unsigned int ub = __bfloat16_as_ushort(__float2bfloat16(b));
    return ua | (ub << 16);
}

__device__ __forceinline__ float bf_lo(unsigned int u) { return __uint_as_float(u << 16); }
__device__ __forceinline__ float bf_hi(unsigned int u) { return __uint_as_float(u & 0xffff0000u); }

// LDS swizzle: identical formula on write and read (both-sides-or-neither rule)
__device__ __forceinline__ int swz(int b, int row) {
    return (b ^ ((row & 7) << 4)) ^ (((b >> 7) & 1) << 4);
}

// ---------------- small utility kernels ----------------

__global__ void zero_f32(float* __restrict__ p, int n) {
    int i = blockIdx.x * 256 + threadIdx.x;
    if (i < n) p[i] = 0.f;
}

__global__ void deg_init(int* __restrict__ deg, int n) {
    int i = blockIdx.x * 256 + threadIdx.x;
    if (i < n) deg[i] = 1;  // self-loop
}

__global__ void deg_count(const int* __restrict__ dst, int* __restrict__ deg, int E) {
    int e = blockIdx.x * 256 + threadIdx.x;
    if (e < E) atomicAdd(&deg[dst[e]], 1);
}

// single-block exclusive scan over n=50000 ints
__global__ __launch_bounds__(1024) void scan_kernel(const int* __restrict__ deg,
                                                    int* __restrict__ rowptr,
                                                    int* __restrict__ cursor, int n) {
    __shared__ int part[1024];
    int t = threadIdx.x;
    int chunk = (n + 1023) >> 10;
    int c0 = t * chunk, c1 = min(c0 + chunk, n);
    int s = 0;
    for (int i = c0; i < c1; ++i) s += deg[i];
    part[t] = s;
    __syncthreads();
    for (int off = 1; off < 1024; off <<= 1) {
        int u = (t >= off) ? part[t - off] : 0;
        __syncthreads();
        part[t] += u;
        __syncthreads();
    }
    int run = part[t] - s;  // exclusive prefix
    for (int i = c0; i < c1; ++i) {
        rowptr[i] = run; cursor[i] = run; run += deg[i];
    }
    if (t == 1023) rowptr[n] = part[1023];
}

__global__ void csr_fill(const int* __restrict__ src, const int* __restrict__ dst,
                         int* __restrict__ cursor, int* __restrict__ csr_src, int E, int N) {
    int e = blockIdx.x * 256 + threadIdx.x;
    if (e >= E + N) return;
    int s, d;
    if (e < E) { s = src[e]; d = dst[e]; } else { s = d = e - E; }
    int pos = atomicAdd(&cursor[d], 1);
    csr_src[pos] = s;
}

// elementwise f32 -> bf16 (weights), n multiple of 4
__global__ void convert_w(const float* __restrict__ W, __hip_bfloat16* __restrict__ Wb, int n) {
    int i4 = (blockIdx.x * 256 + threadIdx.x) * 4;
    if (i4 >= n) return;
    float4 v = *reinterpret_cast<const float4*>(W + i4);
    ushort4 o;
    o.x = __bfloat16_as_ushort(__float2bfloat16(v.x));
    o.y = __bfloat16_as_ushort(__float2bfloat16(v.y));
    o.z = __bfloat16_as_ushort(__float2bfloat16(v.z));
    o.w = __bfloat16_as_ushort(__float2bfloat16(v.w));
    *reinterpret_cast<ushort4*>(Wb + i4) = o;
}

// ---------------- FastKAN via MFMA ----------------
// 64 nodes/block, 256 threads (4 waves). Wave w owns output cols [64w,64w+64) = head w,
// and ALL 64 rows (mf=0..3) -> each 1KB B-fragment feeds 4 independent MFMAs.
// Basis staged in LDS [64][512] bf16 = 64KB, K-phased for IN=256 (2 phases of 512 k).
// LN stats computed once; row-j stats parked in lane j's registers, re-broadcast by shfl.
template <int IN, bool XBF>
__global__ __launch_bounds__(256) void fastkan_mfma(
    const void* __restrict__ xin_v, const float* __restrict__ ln_g, const float* __restrict__ ln_b,
    const __hip_bfloat16* __restrict__ Wb, const float* __restrict__ att_s, const float* __restrict__ att_d,
    __hip_bfloat16* __restrict__ hout, float* __restrict__ as_out, float* __restrict__ ad_out, int nnodes)
{
    constexpr int K   = IN * 4;    // total K (bf16 elements)
    constexpr int NPH = IN / 128;  // K-phases (1 for IN=128, 2 for IN=256)
    constexpr int DPL = IN / 64;   // input dims per lane (2 or 4)
    __shared__ __align__(16) unsigned char bas[64 * 1024];   // [64 rows][512 k] bf16

    int t = threadIdx.x, lane = t & 63, w = t >> 6;
    int lc = lane & 15, lr = lane >> 4;
    int base = blockIdx.x * 64;

    float m_keep = 0.f, r_keep = 0.f;   // lane j holds stats of row w*16+j

    // ---- stats + phase-0 basis: wave w handles rows 16w..16w+15 ----
    for (int j = 0; j < 16; ++j) {
        int r = w * 16 + j;
        int node = base + r;
        unsigned char* rowp = bas + r * 1024;
        if (node < nnodes) {
            float xv[DPL];
            if constexpr (XBF) {
                const unsigned short* xs = (const unsigned short*)xin_v + (size_t)node * IN + DPL * lane;
                if constexpr (DPL == 4) {
                    ushort4 u = *reinterpret_cast<const ushort4*>(xs);
                    xv[0] = bf_lo(u.x); xv[1] = bf_lo(u.y); xv[2] = bf_lo(u.z); xv[3] = bf_lo(u.w);
                } else {
                    ushort2 u = *reinterpret_cast<const ushort2*>(xs);
                    xv[0] = bf_lo(u.x); xv[1] = bf_lo(u.y);
                }
            } else {
                const float* xr = (const float*)xin_v + (size_t)node * IN + DPL * lane;
                if constexpr (DPL == 2) {
                    float2 v2 = *reinterpret_cast<const float2*>(xr);
                    xv[0] = v2.x; xv[1] = v2.y;
                } else {
                    float4 v4 = *reinterpret_cast<const float4*>(xr);
                    xv[0] = v4.x; xv[1] = v4.y; xv[2] = v4.z; xv[3] = v4.w;
                }
            }
            float s = 0.f, sq = 0.f;
            #pragma unroll
            for (int i = 0; i < DPL; ++i) { s += xv[i]; sq += xv[i] * xv[i]; }
            s = wave_sum(s); sq = wave_sum(sq);
            float mean = s * (1.f / IN);
            float var  = sq * (1.f / IN) - mean * mean;
            float rs = rsqrtf(var + 1e-5f);
            if (lane == j) { m_keep = mean; r_keep = rs; }
            // phase-0 write: lanes whose dims fall in [0, 128) (all lanes if NPH==1)
            if (NPH == 1 || lane < 32) {
                unsigned int pk[DPL * 2];
                #pragma unroll
                for (int i = 0; i < DPL; ++i) {
                    int d = DPL * lane + i;
                    float v = (xv[i] - mean) * rs * ln_g[d] + ln_b[d];
                    float t0 = (v + 2.f) * 0.75f;
                    float t1 = (v + 2.f / 3.f) * 0.75f;
                    float t2 = (v - 2.f / 3.f) * 0.75f;
                    float t3 = (v - 2.f) * 0.75f;
                    pk[2 * i]     = pack_bf2(__expf(-t0 * t0), __expf(-t1 * t1));
                    pk[2 * i + 1] = pack_bf2(__expf(-t2 * t2), __expf(-t3 * t3));
                }
                #pragma unroll
                for (int q = 0; q < DPL / 2; ++q) {
                    int b = lane * (DPL * 8) + q * 16;
                    uint4 u; u.x = pk[4 * q]; u.y = pk[4 * q + 1]; u.z = pk[4 * q + 2]; u.w = pk[4 * q + 3];
                    *reinterpret_cast<uint4*>(rowp + swz(b, r)) = u;
                }
            }
        } else {
            if (NPH == 1 || lane < 32) {
                uint4 z{};
                #pragma unroll
                for (int q = 0; q < DPL / 2; ++q) {
                    int b = lane * (DPL * 8) + q * 16;
                    *reinterpret_cast<uint4*>(rowp + swz(b, r)) = z;
                }
            }
        }
    }

    // ---- MFMA phases: acc[mf][nf], rows mf*16+lc, cols w*64+nf*16+lc ----
    f32x4 acc[4][4] = {};
    const __hip_bfloat16* wrow = Wb + (size_t)(w * 64 + lc) * K + lr * 8;

    for (int ph = 0; ph < NPH; ++ph) {
        __syncthreads();   // basis for this phase ready
        #pragma unroll 4
        for (int ks = 0; ks < 16; ++ks) {
            int poff = swz(ks * 64 + lr * 16, lc);   // (mf*16+lc)&7 == lc&7
            bfrag a0 = *reinterpret_cast<const bfrag*>(bas + (0 * 16 + lc) * 1024 + poff);
            bfrag a1 = *reinterpret_cast<const bfrag*>(bas + (1 * 16 + lc) * 1024 + poff);
            bfrag a2 = *reinterpret_cast<const bfrag*>(bas + (2 * 16 + lc) * 1024 + poff);
            bfrag a3 = *reinterpret_cast<const bfrag*>(bas + (3 * 16 + lc) * 1024 + poff);
            #pragma unroll
            for (int nf = 0; nf < 4; ++nf) {
                bfrag b = *reinterpret_cast<const bfrag*>(wrow + (size_t)nf * 16 * K + ph * 512 + ks * 32);
                acc[0][nf] = __builtin_amdgcn_mfma_f32_16x16x32_bf16(a0, b, acc[0][nf], 0, 0, 0);
                acc[1][nf] = __builtin_amdgcn_mfma_f32_16x16x32_bf16(a1, b, acc[1][nf], 0, 0, 0);
                acc[2][nf] = __builtin_amdgcn_mfma_f32_16x16x32_bf16(a2, b, acc[2][nf], 0, 0, 0);
                acc[3][nf] = __builtin_amdgcn_mfma_f32_16x16x32_bf16(a3, b, acc[3][nf], 0, 0, 0);
            }
        }
        if (ph + 1 < NPH) {
            __syncthreads();   // all waves done reading phase-0 basis
            // phase-1 basis: dims [128,256) live in lanes 32..63 (d = 4*lane)
            for (int j = 0; j < 16; ++j) {
                int r = w * 16 + j;
                int node = base + r;
                unsigned char* rowp = bas + r * 1024;
                float mean = __shfl(m_keep, j);
                float rs   = __shfl(r_keep, j);
                if (lane >= 32) {
                    if (node < nnodes) {
                        float xv[4];
                        if constexpr (XBF) {
                            const unsigned short* xs = (const unsigned short*)xin_v + (size_t)node * IN + 4 * lane;
                            ushort4 u = *reinterpret_cast<const ushort4*>(xs);
                            xv[0] = bf_lo(u.x); xv[1] = bf_lo(u.y); xv[2] = bf_lo(u.z); xv[3] = bf_lo(u.w);
                        } else {
                            const float* xr = (const float*)xin_v + (size_t)node * IN + 4 * lane;
                            float4 v4 = *reinterpret_cast<const float4*>(xr);
                            xv[0] = v4.x; xv[1] = v4.y; xv[2] = v4.z; xv[3] = v4.w;
                        }
                        unsigned int pk[8];
                        #pragma unroll
                        for (int i = 0; i < 4; ++i) {
                            int d = 4 * lane + i;
                            float v = (xv[i] - mean) * rs * ln_g[d] + ln_b[d];
                            float t0 = (v + 2.f) * 0.75f;
                            float t1 = (v + 2.f / 3.f) * 0.75f;
                            float t2 = (v - 2.f / 3.f) * 0.75f;
                            float t3 = (v - 2.f) * 0.75f;
                            pk[2 * i]     = pack_bf2(__expf(-t0 * t0), __expf(-t1 * t1));
                            pk[2 * i + 1] = pack_bf2(__expf(-t2 * t2), __expf(-t3 * t3));
                        }
                        #pragma unroll
                        for (int q = 0; q < 2; ++q) {
                            int b = (lane - 32) * 32 + q * 16;
                            uint4 u; u.x = pk[4 * q]; u.y = pk[4 * q + 1]; u.z = pk[4 * q + 2]; u.w = pk[4 * q + 3];
                            *reinterpret_cast<uint4*>(rowp + swz(b, r)) = u;
                        }
                    } else {
                        uint4 z{};
                        #pragma unroll
                        for (int q = 0; q < 2; ++q) {
                            int b = (lane - 32) * 32 + q * 16;
                            *reinterpret_cast<uint4*>(rowp + swz(b, r)) = z;
                        }
                    }
                }
            }
        }
    }

    // ---- epilogue: C/D layout col=lane&15, row=(lane>>4)*4+reg ----
    float asw[4], adw[4];
    #pragma unroll
    for (int nf = 0; nf < 4; ++nf) {
        asw[nf] = att_s[w * 64 + nf * 16 + lc];
        adw[nf] = att_d[w * 64 + nf * 16 + lc];
    }
    #pragma unroll
    for (int mf = 0; mf < 4; ++mf) {
        #pragma unroll
        for (int reg = 0; reg < 4; ++reg) {
            int node = base + mf * 16 + lr * 4 + reg;
            bool ok = node < nnodes;
            float ps = 0.f, pd = 0.f;
            #pragma unroll
            for (int nf = 0; nf < 4; ++nf) {
                float v = acc[mf][nf][reg];
                ps = fmaf(v, asw[nf], ps);
                pd = fmaf(v, adw[nf], pd);
                if (ok) hout[(size_t)node * 256 + w * 64 + nf * 16 + lc] = __float2bfloat16(v);
            }
            #pragma unroll
            for (int off = 8; off; off >>= 1) {
                ps += __shfl_xor(ps, off);
                pd += __shfl_xor(pd, off);
            }
            if (ok && lc == 0) {
                as_out[node * 4 + w] = ps;
                ad_out[node * 4 + w] = pd;
            }
        }
    }
}

// ---------------- fused GAT aggregation ----------------
// Block per dst node; 4 waves split the edge list (stride-4 interleave).
// Lane owns 4 columns (uint2 = 8B gather per edge). Partials combined in LDS.
__global__ __launch_bounds__(256) void gat_agg(
    const int* __restrict__ rowptr, const int* __restrict__ csr_src,
    const float* __restrict__ as_, const float* __restrict__ ad_,
    const __hip_bfloat16* __restrict__ h, const float* __restrict__ bias,
    __hip_bfloat16* __restrict__ out)
{
    __shared__ float accs[4][256];
    __shared__ float ses[4][4];
    int d = blockIdx.x, t = threadIdx.x, w = t >> 6, lane = t & 63;
    int head = lane >> 4;                 // cols lane*4..lane*4+3 are in head lane>>4
    int r0 = rowptr[d], r1 = rowptr[d + 1];
    float adv = ad_[d * 4 + head];
    const unsigned char* hb = (const unsigned char*)h;
    size_t loff = (size_t)lane * 8;

    float a0 = 0.f, a1 = 0.f, a2 = 0.f, a3 = 0.f, se = 0.f;
    int r = r0 + w;
    for (; r + 8 <= r1; r += 8) {
        int s0 = csr_src[r], s1 = csr_src[r + 4];
        float v0 = as_[s0 * 4 + head], v1 = as_[s1 * 4 + head];
        uint2 h0 = *reinterpret_cast<const uint2*>(hb + (size_t)s0 * 512 + loff);
        uint2 h1 = *reinterpret_cast<const uint2*>(hb + (size_t)s1 * 512 + loff);
        float e0 = v0 + adv; e0 = e0 > 0.f ? e0 : 0.2f * e0; e0 = __expf(e0);
        float e1 = v1 + adv; e1 = e1 > 0.f ? e1 : 0.2f * e1; e1 = __expf(e1);
        a0 = fmaf(e0, bf_lo(h0.x), a0); a1 = fmaf(e0, bf_hi(h0.x), a1);
        a2 = fmaf(e0, bf_lo(h0.y), a2); a3 = fmaf(e0, bf_hi(h0.y), a3);
        a0 = fmaf(e1, bf_lo(h1.x), a0); a1 = fmaf(e1, bf_hi(h1.x), a1);
        a2 = fmaf(e1, bf_lo(h1.y), a2); a3 = fmaf(e1, bf_hi(h1.y), a3);
        se += e0 + e1;
    }
    for (; r < r1; r += 4) {
        int s0 = csr_src[r];
        float v0 = as_[s0 * 4 + head];
        uint2 h0 = *reinterpret_cast<const uint2*>(hb + (size_t)s0 * 512 + loff);
        float e0 = v0 + adv; e0 = e0 > 0.f ? e0 : 0.2f * e0; e0 = __expf(e0);
        a0 = fmaf(e0, bf_lo(h0.x), a0); a1 = fmaf(e0, bf_hi(h0.x), a1);
        a2 = fmaf(e0, bf_lo(h0.y), a2); a3 = fmaf(e0, bf_hi(h0.y), a3);
        se += e0;
    }

    float4 av; av.x = a0; av.y = a1; av.z = a2; av.w = a3;
    *reinterpret_cast<float4*>(&accs[w][lane * 4]) = av;
    if ((lane & 15) == 0) ses[w][head] = se;
    __syncthreads();

    // combine: thread t owns column t
    float tot = accs[0][t] + accs[1][t] + accs[2][t] + accs[3][t];
    int hh = t >> 6;
    float sed = ses[0][hh] + ses[1][hh] + ses[2][hh] + ses[3][hh];
    float val = tot / sed + bias[t];
    val = val / (1.f + __expf(-val));  // silu
    out[(size_t)d * 256 + t] = __float2bfloat16(val);
}

// segment-sum pooling over sorted batch: block = (graph g, row-quarter q).
__global__ __launch_bounds__(256) void pool_kernel(
    const __hip_bfloat16* __restrict__ xo, const int* __restrict__ batch,
    float* __restrict__ pooled, int N)
{
    int g = blockIdx.x >> 2, q = blockIdx.x & 3, t = threadIdx.x;
    int lo = 0, hi = N;
    while (lo < hi) { int m = (lo + hi) >> 1; if (batch[m] < g) lo = m + 1; else hi = m; }
    int start = lo;
    hi = N;
    while (lo < hi) { int m = (lo + hi) >> 1; if (batch[m] <= g) lo = m + 1; else hi = m; }
    int end = lo;
    const unsigned short* xu = (const unsigned short*)xo;
    float acc = 0.f;
    for (int r = start + q; r < end; r += 4)
        acc += bf_lo(xu[(size_t)r * 256 + t]);
    atomicAdd(&pooled[g * 256 + t], acc);
}

// readout: LN -> RBF -> [16] logits -> log_softmax, one block per graph
__global__ __launch_bounds__(256) void readout_kernel(
    const float* __restrict__ pooled, const float* __restrict__ ln_g, const float* __restrict__ ln_b,
    const float* __restrict__ Wr, float* __restrict__ out)
{
    __shared__ __align__(16) float bas[1024];
    __shared__ float red[8];
    __shared__ float part[16][17];
    int t = threadIdx.x, lane = t & 63, w = t >> 6;
    int g = blockIdx.x;
    float val = pooled[g * 256 + t];
    float s = wave_sum(val), sq = wave_sum(val * val);
    if (lane == 0) { red[w] = s; red[4 + w] = sq; }
    __syncthreads();
    float stot = red[0] + red[1] + red[2] + red[3];
    float sqtot = red[4] + red[5] + red[6] + red[7];
    float mean = stot * (1.f / 256), var = sqtot * (1.f / 256) - mean * mean;
    float rs = rsqrtf(var + 1e-5f);
    float v = (val - mean) * rs * ln_g[t] + ln_b[t];
    float t0 = (v + 2.f) * 0.75f;
    float t1 = (v + 2.f / 3.f) * 0.75f;
    float t2 = (v - 2.f / 3.f) * 0.75f;
    float t3 = (v - 2.f) * 0.75f;
    float4 e4;
    e4.x = __expf(-t0 * t0); e4.y = __expf(-t1 * t1);
    e4.z = __expf(-t2 * t2); e4.w = __expf(-t3 * t3);
    reinterpret_cast<float4*>(bas)[t] = e4;
    __syncthreads();
    int o = t & 15, slice = t >> 4;
    float p = 0.f;
    const float* wrow = Wr + o * 1024 + slice * 64;
    const float* brow = bas + slice * 64;
    #pragma unroll 8
    for (int kk = 0; kk < 64; ++kk) p = fmaf(brow[kk], wrow[kk], p);
    part[o][slice] = p;
    __syncthreads();
    if (t < 16) {
        float l = 0.f;
        #pragma unroll
        for (int s2 = 0; s2 < 16; ++s2) l += part[t][s2];
        float m = l;
        #pragma unroll
        for (int off = 8; off; off >>= 1) m = fmaxf(m, __shfl_xor(m, off));
        float ex = __expf(l - m);
        float ssum = ex;
        #pragma unroll
        for (int off = 8; off; off >>= 1) ssum += __shfl_xor(ssum, off);
        out[g * 16 + t] = l - m - logf(ssum);
    }
}

// ---------------- launch ----------------

extern "C" void kernel_launch(void* const* d_in, const int* in_sizes, int n_in,
                              void* d_out, int out_size, void* d_ws, size_t ws_size,
                              hipStream_t stream) {
    const float* x      = (const float*)d_in[0];
    const int*   edge   = (const int*)d_in[1];
    const int*   batch  = (const int*)d_in[2];
    const float* ln_g0  = (const float*)d_in[3];
    const float* ln_b0  = (const float*)d_in[4];
    const float* W0     = (const float*)d_in[5];
    const float* att_s0 = (const float*)d_in[6];
    const float* att_d0 = (const float*)d_in[7];
    const float* bias0  = (const float*)d_in[8];
    const float* ln_g1  = (const float*)d_in[9];
    const float* ln_b1  = (const float*)d_in[10];
    const float* W1     = (const float*)d_in[11];
    const float* att_s1 = (const float*)d_in[12];
    const float* att_d1 = (const float*)d_in[13];
    const float* bias1  = (const float*)d_in[14];
    const float* ln_gr  = (const float*)d_in[15];
    const float* ln_br  = (const float*)d_in[16];
    const float* Wr     = (const float*)d_in[17];
    float* outp = (float*)d_out;

    const int N = N_NODES, E = N_EDGES;
    const int* src = edge;
    const int* dst = edge + E;

    unsigned char* ws = (unsigned char*)d_ws;
    size_t off = 0;
    auto alloc = [&](size_t nbytes) {
        unsigned char* p = ws + off;
        off += (nbytes + 255) & ~(size_t)255;
        return (void*)p;
    };
    __hip_bfloat16* W0b   = (__hip_bfloat16*)alloc(256 * 512 * 2);
    __hip_bfloat16* W1b   = (__hip_bfloat16*)alloc(256 * 1024 * 2);
    __hip_bfloat16* h_bf  = (__hip_bfloat16*)alloc((size_t)N * 256 * 2);
    __hip_bfloat16* xmid  = (__hip_bfloat16*)alloc((size_t)N * 256 * 2);  // reused for layer-2 output
    float* as_    = (float*)alloc((size_t)N * 4 * 4);
    float* ad_    = (float*)alloc((size_t)N * 4 * 4);
    int*   rowptr = (int*)alloc((N + 1) * 4);
    int*   cursor = (int*)alloc(N * 4);
    int*   deg    = (int*)alloc(N * 4);
    int*   csr_src= (int*)alloc((size_t)(E + N) * 4);
    float* pooled = (float*)alloc(N_GRAPHS * 256 * 4);

    deg_init<<<(N + 255) / 256, 256, 0, stream>>>(deg, N);
    deg_count<<<(E + 255) / 256, 256, 0, stream>>>(dst, deg, E);
    convert_w<<<(256 * 512 / 4 + 255) / 256, 256, 0, stream>>>(W0, W0b, 256 * 512);
    convert_w<<<(256 * 1024 / 4 + 255) / 256, 256, 0, stream>>>(W1, W1b, 256 * 1024);
    scan_kernel<<<1, 1024, 0, stream>>>(deg, rowptr, cursor, N);
    csr_fill<<<(E + N + 255) / 256, 256, 0, stream>>>(src, dst, cursor, csr_src, E, N);

    // layer 0
    fastkan_mfma<128, false><<<(N + 63) / 64, 256, 0, stream>>>(x, ln_g0, ln_b0, W0b,
                                                                att_s0, att_d0, h_bf, as_, ad_, N);
    gat_agg<<<N, 256, 0, stream>>>(rowptr, csr_src, as_, ad_, h_bf, bias0, xmid);

    // layer 1
    fastkan_mfma<256, true><<<(N + 63) / 64, 256, 0, stream>>>(xmid, ln_g1, ln_b1, W1b,
                                                               att_s1, att_d1, h_bf, as_, ad_, N);
    gat_agg<<<N, 256, 0, stream>>>(rowptr, csr_src, as_, ad_, h_bf, bias1, xmid);

    // pooling (batch sorted -> segmented streaming sum) + readout
    zero_f32<<<(N_GRAPHS * 256 + 255) / 256, 256, 0, stream>>>(pooled, N_GRAPHS * 256);
    pool_kernel<<<N_GRAPHS * 4, 256, 0, stream>>>(xmid, batch, pooled, N);
    readout_kernel<<<N_GRAPHS, 256, 0, stream>>>(pooled, ln_gr, ln_br, Wr, outp);
}

// Round 8
// 701.808 us; speedup vs baseline: 1.1852x; 1.0194x over previous
//
#include <hip/hip_runtime.h>
#include <hip/hip_bf16.h>

#define N_NODES 50000
#define N_EDGES 800000
#define F_IN 128
#define HC 256
#define HEADS 4
#define HID 64
#define N_GRAPHS 64
#define N_CLASSES 16

typedef __attribute__((ext_vector_type(8))) short bfrag;    // 8 bf16 (4 VGPRs)
typedef __attribute__((ext_vector_type(4))) float f32x4;    // MFMA accumulator

__device__ __forceinline__ float wave_sum(float v) {
    #pragma unroll
    for (int off = 32; off > 0; off >>= 1) v += __shfl_xor(v, off);
    return v;
}

__device__ __forceinline__ unsigned int pack_bf2(float a, float b) {
    unsigned int ua = __bfloat16_as_ushort(__float2bfloat16(a));
    unsigned int ub = __bfloat16_as_ushort(__float2bfloat16(b));
    return ua | (ub << 16);
}

__device__ __forceinline__ float bf_lo(unsigned int u) { return __uint_as_float(u << 16); }
__device__ __forceinline__ float bf_hi(unsigned int u) { return __uint_as_float(u & 0xffff0000u); }

// ---------------- small utility kernels ----------------

__global__ void zero_f32(float* __restrict__ p, int n) {
    int i = blockIdx.x * 256 + threadIdx.x;
    if (i < n) p[i] = 0.f;
}

__global__ void deg_init(int* __restrict__ deg, int n) {
    int i = blockIdx.x * 256 + threadIdx.x;
    if (i < n) deg[i] = 1;  // self-loop
}

__global__ void deg_count(const int* __restrict__ dst, int* __restrict__ deg, int E) {
    int e = blockIdx.x * 256 + threadIdx.x;
    if (e < E) atomicAdd(&deg[dst[e]], 1);
}

// single-block exclusive scan over n=50000 ints
__global__ __launch_bounds__(1024) void scan_kernel(const int* __restrict__ deg,
                                                    int* __restrict__ rowptr,
                                                    int* __restrict__ cursor, int n) {
    __shared__ int part[1024];
    int t = threadIdx.x;
    int chunk = (n + 1023) >> 10;
    int c0 = t * chunk, c1 = min(c0 + chunk, n);
    int s = 0;
    for (int i = c0; i < c1; ++i) s += deg[i];
    part[t] = s;
    __syncthreads();
    for (int off = 1; off < 1024; off <<= 1) {
        int u = (t >= off) ? part[t - off] : 0;
        __syncthreads();
        part[t] += u;
        __syncthreads();
    }
    int run = part[t] - s;  // exclusive prefix
    for (int i = c0; i < c1; ++i) {
        rowptr[i] = run; cursor[i] = run; run += deg[i];
    }
    if (t == 1023) rowptr[n] = part[1023];
}

__global__ void csr_fill(const int* __restrict__ src, const int* __restrict__ dst,
                         int* __restrict__ cursor, int* __restrict__ csr_src, int E, int N) {
    int e = blockIdx.x * 256 + threadIdx.x;
    if (e >= E + N) return;
    int s, d;
    if (e < E) { s = src[e]; d = dst[e]; } else { s = d = e - E; }
    int pos = atomicAdd(&cursor[d], 1);
    csr_src[pos] = s;
}

// f32 -> bf16 weights with phase-interleaved K permutation:
// out k-group j (4 elems) = p*64 + l  <-  in k-group = NPH*l + p
__global__ void convert_w_perm(const float* __restrict__ W, __hip_bfloat16* __restrict__ Wb,
                               int KQ /* = K/4 */, int NPH, int total /* = 256*KQ */) {
    int idx = blockIdx.x * 256 + threadIdx.x;
    if (idx >= total) return;
    int o = idx / KQ, j = idx - o * KQ;
    int p = j >> 6, l = j & 63;
    int in4 = NPH * l + p;
    float4 v = *reinterpret_cast<const float4*>(W + (size_t)o * (KQ * 4) + in4 * 4);
    ushort4 u;
    u.x = __bfloat16_as_ushort(__float2bfloat16(v.x));
    u.y = __bfloat16_as_ushort(__float2bfloat16(v.y));
    u.z = __bfloat16_as_ushort(__float2bfloat16(v.z));
    u.w = __bfloat16_as_ushort(__float2bfloat16(v.w));
    *reinterpret_cast<ushort4*>(Wb + (size_t)o * (KQ * 4) + j * 4) = u;
}

// ---------------- FastKAN via MFMA ----------------
// 64 nodes/block, 256 threads (4 waves). Wave w owns output cols [64w,64w+64) = head w,
// rows mf*16+lc (mf=0..3) -> each B-fragment feeds 4 MFMAs.
// K split into NPH phases by dim interleave: phase p = dims d%DPL==p. Each phase's basis
// slab is [64 rows][256 k] bf16 = 32KB LDS. W pre-permuted to match (convert_w_perm).
// LN applied once; normalized values kept packed-bf16 in registers.
template <int IN, bool XBF>
__global__ __launch_bounds__(256, 4) void fastkan_mfma(
    const void* __restrict__ xin_v, const float* __restrict__ ln_g, const float* __restrict__ ln_b,
    const __hip_bfloat16* __restrict__ Wb, const float* __restrict__ att_s, const float* __restrict__ att_d,
    __hip_bfloat16* __restrict__ hout, float* __restrict__ as_out, float* __restrict__ ad_out, int nnodes)
{
    constexpr int K   = IN * 4;    // total K (bf16 elements)
    constexpr int DPL = IN / 64;   // dims per lane (2 or 4) == phase count NPH
    constexpr int NPH = DPL;
    __shared__ __align__(16) unsigned char bas[64 * 512];   // [64 rows][256 k] per phase

    int t = threadIdx.x, lane = t & 63, w = t >> 6;
    int lc = lane & 15, lr = lane >> 4;
    int base = blockIdx.x * 64;

    // ln params for this lane's dims (contiguous DPL*lane .. +DPL-1)
    float lng[DPL], lnb[DPL];
    if constexpr (DPL == 4) {
        float4 g4 = *reinterpret_cast<const float4*>(ln_g + 4 * lane);
        float4 b4 = *reinterpret_cast<const float4*>(ln_b + 4 * lane);
        lng[0] = g4.x; lng[1] = g4.y; lng[2] = g4.z; lng[3] = g4.w;
        lnb[0] = b4.x; lnb[1] = b4.y; lnb[2] = b4.z; lnb[3] = b4.w;
    } else {
        float2 g2 = *reinterpret_cast<const float2*>(ln_g + 2 * lane);
        float2 b2 = *reinterpret_cast<const float2*>(ln_b + 2 * lane);
        lng[0] = g2.x; lng[1] = g2.y;
        lnb[0] = b2.x; lnb[1] = b2.y;
    }

    // ---- stats + normalize: wave w handles rows 16w..16w+15; lane keeps its DPL
    // normalized values per row as packed bf16 (vk[j][i/2]) ----
    unsigned int vk[16][DPL / 2];
    #pragma unroll
    for (int j = 0; j < 16; ++j) {
        int node = base + w * 16 + j;
        float xv[DPL];
        #pragma unroll
        for (int i = 0; i < DPL; ++i) xv[i] = 0.f;
        if (node < nnodes) {
            if constexpr (XBF) {
                const unsigned short* xs = (const unsigned short*)xin_v + (size_t)node * IN + DPL * lane;
                if constexpr (DPL == 4) {
                    uint2 u = *reinterpret_cast<const uint2*>(xs);
                    xv[0] = bf_lo(u.x); xv[1] = bf_hi(u.x);
                    xv[2] = bf_lo(u.y); xv[3] = bf_hi(u.y);
                } else {
                    unsigned int u = *reinterpret_cast<const unsigned int*>(xs);
                    xv[0] = bf_lo(u); xv[1] = bf_hi(u);
                }
            } else {
                const float* xr = (const float*)xin_v + (size_t)node * IN + DPL * lane;
                if constexpr (DPL == 2) {
                    float2 v2 = *reinterpret_cast<const float2*>(xr);
                    xv[0] = v2.x; xv[1] = v2.y;
                } else {
                    float4 v4 = *reinterpret_cast<const float4*>(xr);
                    xv[0] = v4.x; xv[1] = v4.y; xv[2] = v4.z; xv[3] = v4.w;
                }
            }
        }
        float s = 0.f, sq = 0.f;
        #pragma unroll
        for (int i = 0; i < DPL; ++i) { s += xv[i]; sq += xv[i] * xv[i]; }
        s = wave_sum(s); sq = wave_sum(sq);
        float mean = s * (1.f / IN);
        float var  = sq * (1.f / IN) - mean * mean;
        float rs = rsqrtf(var + 1e-5f);
        #pragma unroll
        for (int i = 0; i < DPL; i += 2) {
            float va = (xv[i]     - mean) * rs * lng[i]     + lnb[i];
            float vb = (xv[i + 1] - mean) * rs * lng[i + 1] + lnb[i + 1];
            vk[j][i / 2] = pack_bf2(va, vb);
        }
    }

    // phase-p basis write: row r, lane writes 4 RBF values (8B) of its dim i=p
    auto write_phase = [&](int p) {
        #pragma unroll
        for (int j = 0; j < 16; ++j) {
            int r = w * 16 + j;
            unsigned int pkd = vk[j][p >> 1];
            float v = (p & 1) ? bf_hi(pkd) : bf_lo(pkd);
            float t0 = (v + 2.f) * 0.75f;
            float t1 = (v + 2.f / 3.f) * 0.75f;
            float t2 = (v - 2.f / 3.f) * 0.75f;
            float t3 = (v - 2.f) * 0.75f;
            uint2 o;
            o.x = pack_bf2(__expf(-t0 * t0), __expf(-t1 * t1));
            o.y = pack_bf2(__expf(-t2 * t2), __expf(-t3 * t3));
            *reinterpret_cast<uint2*>(bas + r * 512 + ((lane * 8) ^ ((r & 7) << 4))) = o;
        }
    };

    write_phase(0);

    // ---- MFMA phases: acc[mf][nf], rows mf*16+lc, cols w*64+nf*16+lc ----
    f32x4 acc[4][4] = {};
    const __hip_bfloat16* wrow = Wb + (size_t)(w * 64 + lc) * K + lr * 8;

    #pragma unroll
    for (int p = 0; p < NPH; ++p) {
        __syncthreads();   // phase-p basis visible
        #pragma unroll
        for (int ks = 0; ks < 8; ++ks) {
            int poff = (ks * 64 + lr * 16) ^ ((lc & 7) << 4);
            bfrag a0 = *reinterpret_cast<const bfrag*>(bas + (0 * 16 + lc) * 512 + poff);
            bfrag a1 = *reinterpret_cast<const bfrag*>(bas + (1 * 16 + lc) * 512 + poff);
            bfrag a2 = *reinterpret_cast<const bfrag*>(bas + (2 * 16 + lc) * 512 + poff);
            bfrag a3 = *reinterpret_cast<const bfrag*>(bas + (3 * 16 + lc) * 512 + poff);
            #pragma unroll
            for (int nf = 0; nf < 4; ++nf) {
                bfrag b = *reinterpret_cast<const bfrag*>(wrow + (size_t)nf * 16 * K + p * 256 + ks * 32);
                acc[0][nf] = __builtin_amdgcn_mfma_f32_16x16x32_bf16(a0, b, acc[0][nf], 0, 0, 0);
                acc[1][nf] = __builtin_amdgcn_mfma_f32_16x16x32_bf16(a1, b, acc[1][nf], 0, 0, 0);
                acc[2][nf] = __builtin_amdgcn_mfma_f32_16x16x32_bf16(a2, b, acc[2][nf], 0, 0, 0);
                acc[3][nf] = __builtin_amdgcn_mfma_f32_16x16x32_bf16(a3, b, acc[3][nf], 0, 0, 0);
            }
        }
        if (p + 1 < NPH) {
            __syncthreads();   // all waves done reading phase p
            write_phase(p + 1);
        }
    }

    // ---- epilogue: C/D layout col=lane&15, row=(lane>>4)*4+reg ----
    float asw[4], adw[4];
    #pragma unroll
    for (int nf = 0; nf < 4; ++nf) {
        asw[nf] = att_s[w * 64 + nf * 16 + lc];
        adw[nf] = att_d[w * 64 + nf * 16 + lc];
    }
    #pragma unroll
    for (int mf = 0; mf < 4; ++mf) {
        #pragma unroll
        for (int reg = 0; reg < 4; ++reg) {
            int node = base + mf * 16 + lr * 4 + reg;
            bool ok = node < nnodes;
            float ps = 0.f, pd = 0.f;
            #pragma unroll
            for (int nf = 0; nf < 4; ++nf) {
                float v = acc[mf][nf][reg];
                ps = fmaf(v, asw[nf], ps);
                pd = fmaf(v, adw[nf], pd);
                if (ok) hout[(size_t)node * 256 + w * 64 + nf * 16 + lc] = __float2bfloat16(v);
            }
            #pragma unroll
            for (int off = 8; off; off >>= 1) {
                ps += __shfl_xor(ps, off);
                pd += __shfl_xor(pd, off);
            }
            if (ok && lc == 0) {
                as_out[node * 4 + w] = ps;
                ad_out[node * 4 + w] = pd;
            }
        }
    }
}

// ---------------- fused GAT aggregation ----------------
// Block per dst node; 4 waves split the edge list (stride-4 interleave).
// Lane owns 4 columns (uint2 = 8B gather per edge). Partials combined in LDS.
__global__ __launch_bounds__(256) void gat_agg(
    const int* __restrict__ rowptr, const int* __restrict__ csr_src,
    const float* __restrict__ as_, const float* __restrict__ ad_,
    const __hip_bfloat16* __restrict__ h, const float* __restrict__ bias,
    __hip_bfloat16* __restrict__ out)
{
    __shared__ float accs[4][256];
    __shared__ float ses[4][4];
    int d = blockIdx.x, t = threadIdx.x, w = t >> 6, lane = t & 63;
    int head = lane >> 4;                 // cols lane*4..lane*4+3 are in head lane>>4
    int r0 = rowptr[d], r1 = rowptr[d + 1];
    float adv = ad_[d * 4 + head];
    const unsigned char* hb = (const unsigned char*)h;
    size_t loff = (size_t)lane * 8;

    float a0 = 0.f, a1 = 0.f, a2 = 0.f, a3 = 0.f, se = 0.f;
    int r = r0 + w;
    for (; r + 8 <= r1; r += 8) {
        int s0 = csr_src[r], s1 = csr_src[r + 4];
        float v0 = as_[s0 * 4 + head], v1 = as_[s1 * 4 + head];
        uint2 h0 = *reinterpret_cast<const uint2*>(hb + (size_t)s0 * 512 + loff);
        uint2 h1 = *reinterpret_cast<const uint2*>(hb + (size_t)s1 * 512 + loff);
        float e0 = v0 + adv; e0 = e0 > 0.f ? e0 : 0.2f * e0; e0 = __expf(e0);
        float e1 = v1 + adv; e1 = e1 > 0.f ? e1 : 0.2f * e1; e1 = __expf(e1);
        a0 = fmaf(e0, bf_lo(h0.x), a0); a1 = fmaf(e0, bf_hi(h0.x), a1);
        a2 = fmaf(e0, bf_lo(h0.y), a2); a3 = fmaf(e0, bf_hi(h0.y), a3);
        a0 = fmaf(e1, bf_lo(h1.x), a0); a1 = fmaf(e1, bf_hi(h1.x), a1);
        a2 = fmaf(e1, bf_lo(h1.y), a2); a3 = fmaf(e1, bf_hi(h1.y), a3);
        se += e0 + e1;
    }
    for (; r < r1; r += 4) {
        int s0 = csr_src[r];
        float v0 = as_[s0 * 4 + head];
        uint2 h0 = *reinterpret_cast<const uint2*>(hb + (size_t)s0 * 512 + loff);
        float e0 = v0 + adv; e0 = e0 > 0.f ? e0 : 0.2f * e0; e0 = __expf(e0);
        a0 = fmaf(e0, bf_lo(h0.x), a0); a1 = fmaf(e0, bf_hi(h0.x), a1);
        a2 = fmaf(e0, bf_lo(h0.y), a2); a3 = fmaf(e0, bf_hi(h0.y), a3);
        se += e0;
    }

    float4 av; av.x = a0; av.y = a1; av.z = a2; av.w = a3;
    *reinterpret_cast<float4*>(&accs[w][lane * 4]) = av;
    if ((lane & 15) == 0) ses[w][head] = se;
    __syncthreads();

    // combine: thread t owns column t
    float tot = accs[0][t] + accs[1][t] + accs[2][t] + accs[3][t];
    int hh = t >> 6;
    float sed = ses[0][hh] + ses[1][hh] + ses[2][hh] + ses[3][hh];
    float val = tot / sed + bias[t];
    val = val / (1.f + __expf(-val));  // silu
    out[(size_t)d * 256 + t] = __float2bfloat16(val);
}

// segment-sum pooling over sorted batch: block = (graph g, row-quarter q).
__global__ __launch_bounds__(256) void pool_kernel(
    const __hip_bfloat16* __restrict__ xo, const int* __restrict__ batch,
    float* __restrict__ pooled, int N)
{
    int g = blockIdx.x >> 2, q = blockIdx.x & 3, t = threadIdx.x;
    int lo = 0, hi = N;
    while (lo < hi) { int m = (lo + hi) >> 1; if (batch[m] < g) lo = m + 1; else hi = m; }
    int start = lo;
    hi = N;
    while (lo < hi) { int m = (lo + hi) >> 1; if (batch[m] <= g) lo = m + 1; else hi = m; }
    int end = lo;
    const unsigned short* xu = (const unsigned short*)xo;
    float acc = 0.f;
    for (int r = start + q; r < end; r += 4)
        acc += bf_lo(xu[(size_t)r * 256 + t]);
    atomicAdd(&pooled[g * 256 + t], acc);
}

// readout: LN -> RBF -> [16] logits -> log_softmax, one block per graph
__global__ __launch_bounds__(256) void readout_kernel(
    const float* __restrict__ pooled, const float* __restrict__ ln_g, const float* __restrict__ ln_b,
    const float* __restrict__ Wr, float* __restrict__ out)
{
    __shared__ __align__(16) float bas[1024];
    __shared__ float red[8];
    __shared__ float part[16][17];
    int t = threadIdx.x, lane = t & 63, w = t >> 6;
    int g = blockIdx.x;
    float val = pooled[g * 256 + t];
    float s = wave_sum(val), sq = wave_sum(val * val);
    if (lane == 0) { red[w] = s; red[4 + w] = sq; }
    __syncthreads();
    float stot = red[0] + red[1] + red[2] + red[3];
    float sqtot = red[4] + red[5] + red[6] + red[7];
    float mean = stot * (1.f / 256), var = sqtot * (1.f / 256) - mean * mean;
    float rs = rsqrtf(var + 1e-5f);
    float v = (val - mean) * rs * ln_g[t] + ln_b[t];
    float t0 = (v + 2.f) * 0.75f;
    float t1 = (v + 2.f / 3.f) * 0.75f;
    float t2 = (v - 2.f / 3.f) * 0.75f;
    float t3 = (v - 2.f) * 0.75f;
    float4 e4;
    e4.x = __expf(-t0 * t0); e4.y = __expf(-t1 * t1);
    e4.z = __expf(-t2 * t2); e4.w = __expf(-t3 * t3);
    reinterpret_cast<float4*>(bas)[t] = e4;
    __syncthreads();
    int o = t & 15, slice = t >> 4;
    float p = 0.f;
    const float* wrow = Wr + o * 1024 + slice * 64;
    const float* brow = bas + slice * 64;
    #pragma unroll 8
    for (int kk = 0; kk < 64; ++kk) p = fmaf(brow[kk], wrow[kk], p);
    part[o][slice] = p;
    __syncthreads();
    if (t < 16) {
        float l = 0.f;
        #pragma unroll
        for (int s2 = 0; s2 < 16; ++s2) l += part[t][s2];
        float m = l;
        #pragma unroll
        for (int off = 8; off; off >>= 1) m = fmaxf(m, __shfl_xor(m, off));
        float ex = __expf(l - m);
        float ssum = ex;
        #pragma unroll
        for (int off = 8; off; off >>= 1) ssum += __shfl_xor(ssum, off);
        out[g * 16 + t] = l - m - logf(ssum);
    }
}

// ---------------- launch ----------------

extern "C" void kernel_launch(void* const* d_in, const int* in_sizes, int n_in,
                              void* d_out, int out_size, void* d_ws, size_t ws_size,
                              hipStream_t stream) {
    const float* x      = (const float*)d_in[0];
    const int*   edge   = (const int*)d_in[1];
    const int*   batch  = (const int*)d_in[2];
    const float* ln_g0  = (const float*)d_in[3];
    const float* ln_b0  = (const float*)d_in[4];
    const float* W0     = (const float*)d_in[5];
    const float* att_s0 = (const float*)d_in[6];
    const float* att_d0 = (const float*)d_in[7];
    const float* bias0  = (const float*)d_in[8];
    const float* ln_g1  = (const float*)d_in[9];
    const float* ln_b1  = (const float*)d_in[10];
    const float* W1     = (const float*)d_in[11];
    const float* att_s1 = (const float*)d_in[12];
    const float* att_d1 = (const float*)d_in[13];
    const float* bias1  = (const float*)d_in[14];
    const float* ln_gr  = (const float*)d_in[15];
    const float* ln_br  = (const float*)d_in[16];
    const float* Wr     = (const float*)d_in[17];
    float* outp = (float*)d_out;

    const int N = N_NODES, E = N_EDGES;
    const int* src = edge;
    const int* dst = edge + E;

    unsigned char* ws = (unsigned char*)d_ws;
    size_t off = 0;
    auto alloc = [&](size_t nbytes) {
        unsigned char* p = ws + off;
        off += (nbytes + 255) & ~(size_t)255;
        return (void*)p;
    };
    __hip_bfloat16* W0b   = (__hip_bfloat16*)alloc(256 * 512 * 2);
    __hip_bfloat16* W1b   = (__hip_bfloat16*)alloc(256 * 1024 * 2);
    __hip_bfloat16* h_bf  = (__hip_bfloat16*)alloc((size_t)N * 256 * 2);
    __hip_bfloat16* xmid  = (__hip_bfloat16*)alloc((size_t)N * 256 * 2);  // reused for layer-2 output
    float* as_    = (float*)alloc((size_t)N * 4 * 4);
    float* ad_    = (float*)alloc((size_t)N * 4 * 4);
    int*   rowptr = (int*)alloc((N + 1) * 4);
    int*   cursor = (int*)alloc(N * 4);
    int*   deg    = (int*)alloc(N * 4);
    int*   csr_src= (int*)alloc((size_t)(E + N) * 4);
    float* pooled = (float*)alloc(N_GRAPHS * 256 * 4);

    deg_init<<<(N + 255) / 256, 256, 0, stream>>>(deg, N);
    deg_count<<<(E + 255) / 256, 256, 0, stream>>>(dst, deg, E);
    convert_w_perm<<<(256 * 128 + 255) / 256, 256, 0, stream>>>(W0, W0b, 128, 2, 256 * 128);
    convert_w_perm<<<(256 * 256 + 255) / 256, 256, 0, stream>>>(W1, W1b, 256, 4, 256 * 256);
    scan_kernel<<<1, 1024, 0, stream>>>(deg, rowptr, cursor, N);
    csr_fill<<<(E + N + 255) / 256, 256, 0, stream>>>(src, dst, cursor, csr_src, E, N);

    // layer 0
    fastkan_mfma<128, false><<<(N + 63) / 64, 256, 0, stream>>>(x, ln_g0, ln_b0, W0b,
                                                                att_s0, att_d0, h_bf, as_, ad_, N);
    gat_agg<<<N, 256, 0, stream>>>(rowptr, csr_src, as_, ad_, h_bf, bias0, xmid);

    // layer 1
    fastkan_mfma<256, true><<<(N + 63) / 64, 256, 0, stream>>>(xmid, ln_g1, ln_b1, W1b,
                                                               att_s1, att_d1, h_bf, as_, ad_, N);
    gat_agg<<<N, 256, 0, stream>>>(rowptr, csr_src, as_, ad_, h_bf, bias1, xmid);

    // pooling (batch sorted -> segmented streaming sum) + readout
    zero_f32<<<(N_GRAPHS * 256 + 255) / 256, 256, 0, stream>>>(pooled, N_GRAPHS * 256);
    pool_kernel<<<N_GRAPHS * 4, 256, 0, stream>>>(xmid, batch, pooled, N);
    readout_kernel<<<N_GRAPHS, 256, 0, stream>>>(pooled, ln_gr, ln_br, Wr, outp);
}

// Round 9
// 603.783 us; speedup vs baseline: 1.3777x; 1.1624x over previous
//
#include <hip/hip_runtime.h>
#include <hip/hip_bf16.h>

#define N_NODES 50000
#define N_EDGES 800000
#define F_IN 128
#define HC 256
#define HEADS 4
#define HID 64
#define N_GRAPHS 64
#define N_CLASSES 16

typedef __attribute__((ext_vector_type(8))) short bfrag;    // 8 bf16 (4 VGPRs)
typedef __attribute__((ext_vector_type(4))) float f32x4;    // MFMA accumulator

__device__ __forceinline__ float wave_sum(float v) {
    #pragma unroll
    for (int off = 32; off > 0; off >>= 1) v += __shfl_xor(v, off);
    return v;
}

__device__ __forceinline__ unsigned int pack_bf2(float a, float b) {
    unsigned int ua = __bfloat16_as_ushort(__float2bfloat16(a));
    unsigned int ub = __bfloat16_as_ushort(__float2bfloat16(b));
    return ua | (ub << 16);
}

__device__ __forceinline__ float bf_lo(unsigned int u) { return __uint_as_float(u << 16); }
__device__ __forceinline__ float bf_hi(unsigned int u) { return __uint_as_float(u & 0xffff0000u); }

// ---------------- small utility kernels ----------------

__global__ void zero_f32(float* __restrict__ p, int n) {
    int i = blockIdx.x * 256 + threadIdx.x;
    if (i < n) p[i] = 0.f;
}

__global__ void deg_init(int* __restrict__ deg, int n) {
    int i = blockIdx.x * 256 + threadIdx.x;
    if (i < n) deg[i] = 1;  // self-loop
}

__global__ void deg_count(const int* __restrict__ dst, int* __restrict__ deg, int E) {
    int e = blockIdx.x * 256 + threadIdx.x;
    if (e < E) atomicAdd(&deg[dst[e]], 1);
}

// ---- parallel 3-stage exclusive scan over deg[n] -> rowptr/cursor ----
// stage 1: per-block (256-wide) scan; rowptr gets pre-offset exclusive values
__global__ __launch_bounds__(256) void scan_blocks(const int* __restrict__ deg,
                                                   int* __restrict__ rowptr,
                                                   int* __restrict__ blocksum, int n) {
    __shared__ int wsum[4];
    int i = blockIdx.x * 256 + threadIdx.x;
    int lane = threadIdx.x & 63, w = threadIdx.x >> 6;
    int v = (i < n) ? deg[i] : 0;
    int x = v;
    #pragma unroll
    for (int off = 1; off < 64; off <<= 1) {
        int y = __shfl_up(x, off);
        if (lane >= off) x += y;
    }
    if (lane == 63) wsum[w] = x;
    __syncthreads();
    int add = 0;
    #pragma unroll
    for (int k = 0; k < 4; ++k) add += (k < w) ? wsum[k] : 0;
    int incl = x + add;
    if (i < n) rowptr[i] = incl - v;             // exclusive, pre-offset
    if (threadIdx.x == 255) blocksum[blockIdx.x] = incl;  // block total
}

// stage 2: single-block scan of block totals -> exclusive block offsets (nb <= 256)
__global__ __launch_bounds__(256) void scan_tops(int* __restrict__ blocksum, int nb) {
    __shared__ int s[256];
    int t = threadIdx.x;
    int v = (t < nb) ? blocksum[t] : 0;
    s[t] = v;
    __syncthreads();
    for (int off = 1; off < 256; off <<= 1) {
        int u = (t >= off) ? s[t - off] : 0;
        __syncthreads();
        s[t] += u;
        __syncthreads();
    }
    if (t < nb) blocksum[t] = s[t] - v;          // exclusive offset
}

// stage 3: add block offsets; fill cursor; write rowptr[n] = total (known = E+N)
__global__ __launch_bounds__(256) void scan_apply(const int* __restrict__ blocksum,
                                                  int* __restrict__ rowptr,
                                                  int* __restrict__ cursor, int n, int total) {
    int i = blockIdx.x * 256 + threadIdx.x;
    if (i < n) {
        int v = rowptr[i] + blocksum[blockIdx.x];
        rowptr[i] = v; cursor[i] = v;
    }
    if (i == 0) rowptr[n] = total;
}

__global__ void csr_fill(const int* __restrict__ src, const int* __restrict__ dst,
                         int* __restrict__ cursor, int* __restrict__ csr_src, int E, int N) {
    int e = blockIdx.x * 256 + threadIdx.x;
    if (e >= E + N) return;
    int s, d;
    if (e < E) { s = src[e]; d = dst[e]; } else { s = d = e - E; }
    int pos = atomicAdd(&cursor[d], 1);
    csr_src[pos] = s;
}

// f32 -> bf16 weights with phase-interleaved K permutation:
// out k-group j (4 elems) = p*64 + l  <-  in k-group = NPH*l + p
__global__ void convert_w_perm(const float* __restrict__ W, __hip_bfloat16* __restrict__ Wb,
                               int KQ /* = K/4 */, int NPH, int total /* = 256*KQ */) {
    int idx = blockIdx.x * 256 + threadIdx.x;
    if (idx >= total) return;
    int o = idx / KQ, j = idx - o * KQ;
    int p = j >> 6, l = j & 63;
    int in4 = NPH * l + p;
    float4 v = *reinterpret_cast<const float4*>(W + (size_t)o * (KQ * 4) + in4 * 4);
    ushort4 u;
    u.x = __bfloat16_as_ushort(__float2bfloat16(v.x));
    u.y = __bfloat16_as_ushort(__float2bfloat16(v.y));
    u.z = __bfloat16_as_ushort(__float2bfloat16(v.z));
    u.w = __bfloat16_as_ushort(__float2bfloat16(v.w));
    *reinterpret_cast<ushort4*>(Wb + (size_t)o * (KQ * 4) + j * 4) = u;
}

// ---------------- FastKAN via MFMA ----------------
// 64 nodes/block, 256 threads (4 waves). Wave w owns output cols [64w,64w+64) = head w,
// rows mf*16+lc (mf=0..3) -> each B-fragment feeds 4 MFMAs.
// K split into NPH phases by dim interleave: phase p = dims d%DPL==p. Each phase's basis
// slab is [64 rows][256 k] bf16 = 32KB LDS. W pre-permuted to match (convert_w_perm).
// LN applied once; normalized values kept packed-bf16 in registers.
template <int IN, bool XBF>
__global__ __launch_bounds__(256, 4) void fastkan_mfma(
    const void* __restrict__ xin_v, const float* __restrict__ ln_g, const float* __restrict__ ln_b,
    const __hip_bfloat16* __restrict__ Wb, const float* __restrict__ att_s, const float* __restrict__ att_d,
    __hip_bfloat16* __restrict__ hout, float* __restrict__ as_out, float* __restrict__ ad_out, int nnodes)
{
    constexpr int K   = IN * 4;    // total K (bf16 elements)
    constexpr int DPL = IN / 64;   // dims per lane (2 or 4) == phase count NPH
    constexpr int NPH = DPL;
    __shared__ __align__(16) unsigned char bas[64 * 512];   // [64 rows][256 k] per phase

    int t = threadIdx.x, lane = t & 63, w = t >> 6;
    int lc = lane & 15, lr = lane >> 4;
    int base = blockIdx.x * 64;

    // ln params for this lane's dims (contiguous DPL*lane .. +DPL-1)
    float lng[DPL], lnb[DPL];
    if constexpr (DPL == 4) {
        float4 g4 = *reinterpret_cast<const float4*>(ln_g + 4 * lane);
        float4 b4 = *reinterpret_cast<const float4*>(ln_b + 4 * lane);
        lng[0] = g4.x; lng[1] = g4.y; lng[2] = g4.z; lng[3] = g4.w;
        lnb[0] = b4.x; lnb[1] = b4.y; lnb[2] = b4.z; lnb[3] = b4.w;
    } else {
        float2 g2 = *reinterpret_cast<const float2*>(ln_g + 2 * lane);
        float2 b2 = *reinterpret_cast<const float2*>(ln_b + 2 * lane);
        lng[0] = g2.x; lng[1] = g2.y;
        lnb[0] = b2.x; lnb[1] = b2.y;
    }

    // ---- stats + normalize: wave w handles rows 16w..16w+15; lane keeps its DPL
    // normalized values per row as packed bf16 (vk[j][i/2]) ----
    unsigned int vk[16][DPL / 2];
    #pragma unroll
    for (int j = 0; j < 16; ++j) {
        int node = base + w * 16 + j;
        float xv[DPL];
        #pragma unroll
        for (int i = 0; i < DPL; ++i) xv[i] = 0.f;
        if (node < nnodes) {
            if constexpr (XBF) {
                const unsigned short* xs = (const unsigned short*)xin_v + (size_t)node * IN + DPL * lane;
                if constexpr (DPL == 4) {
                    uint2 u = *reinterpret_cast<const uint2*>(xs);
                    xv[0] = bf_lo(u.x); xv[1] = bf_hi(u.x);
                    xv[2] = bf_lo(u.y); xv[3] = bf_hi(u.y);
                } else {
                    unsigned int u = *reinterpret_cast<const unsigned int*>(xs);
                    xv[0] = bf_lo(u); xv[1] = bf_hi(u);
                }
            } else {
                const float* xr = (const float*)xin_v + (size_t)node * IN + DPL * lane;
                if constexpr (DPL == 2) {
                    float2 v2 = *reinterpret_cast<const float2*>(xr);
                    xv[0] = v2.x; xv[1] = v2.y;
                } else {
                    float4 v4 = *reinterpret_cast<const float4*>(xr);
                    xv[0] = v4.x; xv[1] = v4.y; xv[2] = v4.z; xv[3] = v4.w;
                }
            }
        }
        float s = 0.f, sq = 0.f;
        #pragma unroll
        for (int i = 0; i < DPL; ++i) { s += xv[i]; sq += xv[i] * xv[i]; }
        s = wave_sum(s); sq = wave_sum(sq);
        float mean = s * (1.f / IN);
        float var  = sq * (1.f / IN) - mean * mean;
        float rs = rsqrtf(var + 1e-5f);
        #pragma unroll
        for (int i = 0; i < DPL; i += 2) {
            float va = (xv[i]     - mean) * rs * lng[i]     + lnb[i];
            float vb = (xv[i + 1] - mean) * rs * lng[i + 1] + lnb[i + 1];
            vk[j][i / 2] = pack_bf2(va, vb);
        }
    }

    // phase-p basis write: row r, lane writes 4 RBF values (8B) of its dim i=p
    auto write_phase = [&](int p) {
        #pragma unroll
        for (int j = 0; j < 16; ++j) {
            int r = w * 16 + j;
            unsigned int pkd = vk[j][p >> 1];
            float v = (p & 1) ? bf_hi(pkd) : bf_lo(pkd);
            float t0 = (v + 2.f) * 0.75f;
            float t1 = (v + 2.f / 3.f) * 0.75f;
            float t2 = (v - 2.f / 3.f) * 0.75f;
            float t3 = (v - 2.f) * 0.75f;
            uint2 o;
            o.x = pack_bf2(__expf(-t0 * t0), __expf(-t1 * t1));
            o.y = pack_bf2(__expf(-t2 * t2), __expf(-t3 * t3));
            *reinterpret_cast<uint2*>(bas + r * 512 + ((lane * 8) ^ ((r & 7) << 4))) = o;
        }
    };

    write_phase(0);

    // ---- MFMA phases: acc[mf][nf], rows mf*16+lc, cols w*64+nf*16+lc ----
    f32x4 acc[4][4] = {};
    const __hip_bfloat16* wrow = Wb + (size_t)(w * 64 + lc) * K + lr * 8;

    #pragma unroll
    for (int p = 0; p < NPH; ++p) {
        __syncthreads();   // phase-p basis visible
        #pragma unroll
        for (int ks = 0; ks < 8; ++ks) {
            int poff = (ks * 64 + lr * 16) ^ ((lc & 7) << 4);
            bfrag a0 = *reinterpret_cast<const bfrag*>(bas + (0 * 16 + lc) * 512 + poff);
            bfrag a1 = *reinterpret_cast<const bfrag*>(bas + (1 * 16 + lc) * 512 + poff);
            bfrag a2 = *reinterpret_cast<const bfrag*>(bas + (2 * 16 + lc) * 512 + poff);
            bfrag a3 = *reinterpret_cast<const bfrag*>(bas + (3 * 16 + lc) * 512 + poff);
            #pragma unroll
            for (int nf = 0; nf < 4; ++nf) {
                bfrag b = *reinterpret_cast<const bfrag*>(wrow + (size_t)nf * 16 * K + p * 256 + ks * 32);
                acc[0][nf] = __builtin_amdgcn_mfma_f32_16x16x32_bf16(a0, b, acc[0][nf], 0, 0, 0);
                acc[1][nf] = __builtin_amdgcn_mfma_f32_16x16x32_bf16(a1, b, acc[1][nf], 0, 0, 0);
                acc[2][nf] = __builtin_amdgcn_mfma_f32_16x16x32_bf16(a2, b, acc[2][nf], 0, 0, 0);
                acc[3][nf] = __builtin_amdgcn_mfma_f32_16x16x32_bf16(a3, b, acc[3][nf], 0, 0, 0);
            }
        }
        if (p + 1 < NPH) {
            __syncthreads();   // all waves done reading phase p
            write_phase(p + 1);
        }
    }

    // ---- epilogue: C/D layout col=lane&15, row=(lane>>4)*4+reg ----
    float asw[4], adw[4];
    #pragma unroll
    for (int nf = 0; nf < 4; ++nf) {
        asw[nf] = att_s[w * 64 + nf * 16 + lc];
        adw[nf] = att_d[w * 64 + nf * 16 + lc];
    }
    #pragma unroll
    for (int mf = 0; mf < 4; ++mf) {
        #pragma unroll
        for (int reg = 0; reg < 4; ++reg) {
            int node = base + mf * 16 + lr * 4 + reg;
            bool ok = node < nnodes;
            float ps = 0.f, pd = 0.f;
            #pragma unroll
            for (int nf = 0; nf < 4; ++nf) {
                float v = acc[mf][nf][reg];
                ps = fmaf(v, asw[nf], ps);
                pd = fmaf(v, adw[nf], pd);
                if (ok) hout[(size_t)node * 256 + w * 64 + nf * 16 + lc] = __float2bfloat16(v);
            }
            #pragma unroll
            for (int off = 8; off; off >>= 1) {
                ps += __shfl_xor(ps, off);
                pd += __shfl_xor(pd, off);
            }
            if (ok && lc == 0) {
                as_out[node * 4 + w] = ps;
                ad_out[node * 4 + w] = pd;
            }
        }
    }
}

// ---------------- fused GAT aggregation ----------------
// Block per dst node; 4 waves split the edge list (stride-4 interleave).
// Lane owns 4 columns (uint2 = 8B gather per edge). Partials combined in LDS.
__global__ __launch_bounds__(256) void gat_agg(
    const int* __restrict__ rowptr, const int* __restrict__ csr_src,
    const float* __restrict__ as_, const float* __restrict__ ad_,
    const __hip_bfloat16* __restrict__ h, const float* __restrict__ bias,
    __hip_bfloat16* __restrict__ out)
{
    __shared__ float accs[4][256];
    __shared__ float ses[4][4];
    int d = blockIdx.x, t = threadIdx.x, w = t >> 6, lane = t & 63;
    int head = lane >> 4;                 // cols lane*4..lane*4+3 are in head lane>>4
    int r0 = rowptr[d], r1 = rowptr[d + 1];
    float adv = ad_[d * 4 + head];
    const unsigned char* hb = (const unsigned char*)h;
    size_t loff = (size_t)lane * 8;

    float a0 = 0.f, a1 = 0.f, a2 = 0.f, a3 = 0.f, se = 0.f;
    int r = r0 + w;
    for (; r + 8 <= r1; r += 8) {
        int s0 = csr_src[r], s1 = csr_src[r + 4];
        float v0 = as_[s0 * 4 + head], v1 = as_[s1 * 4 + head];
        uint2 h0 = *reinterpret_cast<const uint2*>(hb + (size_t)s0 * 512 + loff);
        uint2 h1 = *reinterpret_cast<const uint2*>(hb + (size_t)s1 * 512 + loff);
        float e0 = v0 + adv; e0 = e0 > 0.f ? e0 : 0.2f * e0; e0 = __expf(e0);
        float e1 = v1 + adv; e1 = e1 > 0.f ? e1 : 0.2f * e1; e1 = __expf(e1);
        a0 = fmaf(e0, bf_lo(h0.x), a0); a1 = fmaf(e0, bf_hi(h0.x), a1);
        a2 = fmaf(e0, bf_lo(h0.y), a2); a3 = fmaf(e0, bf_hi(h0.y), a3);
        a0 = fmaf(e1, bf_lo(h1.x), a0); a1 = fmaf(e1, bf_hi(h1.x), a1);
        a2 = fmaf(e1, bf_lo(h1.y), a2); a3 = fmaf(e1, bf_hi(h1.y), a3);
        se += e0 + e1;
    }
    for (; r < r1; r += 4) {
        int s0 = csr_src[r];
        float v0 = as_[s0 * 4 + head];
        uint2 h0 = *reinterpret_cast<const uint2*>(hb + (size_t)s0 * 512 + loff);
        float e0 = v0 + adv; e0 = e0 > 0.f ? e0 : 0.2f * e0; e0 = __expf(e0);
        a0 = fmaf(e0, bf_lo(h0.x), a0); a1 = fmaf(e0, bf_hi(h0.x), a1);
        a2 = fmaf(e0, bf_lo(h0.y), a2); a3 = fmaf(e0, bf_hi(h0.y), a3);
        se += e0;
    }

    float4 av; av.x = a0; av.y = a1; av.z = a2; av.w = a3;
    *reinterpret_cast<float4*>(&accs[w][lane * 4]) = av;
    if ((lane & 15) == 0) ses[w][head] = se;
    __syncthreads();

    // combine: thread t owns column t
    float tot = accs[0][t] + accs[1][t] + accs[2][t] + accs[3][t];
    int hh = t >> 6;
    float sed = ses[0][hh] + ses[1][hh] + ses[2][hh] + ses[3][hh];
    float val = tot / sed + bias[t];
    val = val / (1.f + __expf(-val));  // silu
    out[(size_t)d * 256 + t] = __float2bfloat16(val);
}

// segment-sum pooling over sorted batch: block = (graph g, row-quarter q).
__global__ __launch_bounds__(256) void pool_kernel(
    const __hip_bfloat16* __restrict__ xo, const int* __restrict__ batch,
    float* __restrict__ pooled, int N)
{
    int g = blockIdx.x >> 2, q = blockIdx.x & 3, t = threadIdx.x;
    int lo = 0, hi = N;
    while (lo < hi) { int m = (lo + hi) >> 1; if (batch[m] < g) lo = m + 1; else hi = m; }
    int start = lo;
    hi = N;
    while (lo < hi) { int m = (lo + hi) >> 1; if (batch[m] <= g) lo = m + 1; else hi = m; }
    int end = lo;
    const unsigned short* xu = (const unsigned short*)xo;
    float acc = 0.f;
    for (int r = start + q; r < end; r += 4)
        acc += bf_lo(xu[(size_t)r * 256 + t]);
    atomicAdd(&pooled[g * 256 + t], acc);
}

// readout: LN -> RBF -> [16] logits -> log_softmax, one block per graph
__global__ __launch_bounds__(256) void readout_kernel(
    const float* __restrict__ pooled, const float* __restrict__ ln_g, const float* __restrict__ ln_b,
    const float* __restrict__ Wr, float* __restrict__ out)
{
    __shared__ __align__(16) float bas[1024];
    __shared__ float red[8];
    __shared__ float part[16][17];
    int t = threadIdx.x, lane = t & 63, w = t >> 6;
    int g = blockIdx.x;
    float val = pooled[g * 256 + t];
    float s = wave_sum(val), sq = wave_sum(val * val);
    if (lane == 0) { red[w] = s; red[4 + w] = sq; }
    __syncthreads();
    float stot = red[0] + red[1] + red[2] + red[3];
    float sqtot = red[4] + red[5] + red[6] + red[7];
    float mean = stot * (1.f / 256), var = sqtot * (1.f / 256) - mean * mean;
    float rs = rsqrtf(var + 1e-5f);
    float v = (val - mean) * rs * ln_g[t] + ln_b[t];
    float t0 = (v + 2.f) * 0.75f;
    float t1 = (v + 2.f / 3.f) * 0.75f;
    float t2 = (v - 2.f / 3.f) * 0.75f;
    float t3 = (v - 2.f) * 0.75f;
    float4 e4;
    e4.x = __expf(-t0 * t0); e4.y = __expf(-t1 * t1);
    e4.z = __expf(-t2 * t2); e4.w = __expf(-t3 * t3);
    reinterpret_cast<float4*>(bas)[t] = e4;
    __syncthreads();
    int o = t & 15, slice = t >> 4;
    float p = 0.f;
    const float* wrow = Wr + o * 1024 + slice * 64;
    const float* brow = bas + slice * 64;
    #pragma unroll 8
    for (int kk = 0; kk < 64; ++kk) p = fmaf(brow[kk], wrow[kk], p);
    part[o][slice] = p;
    __syncthreads();
    if (t < 16) {
        float l = 0.f;
        #pragma unroll
        for (int s2 = 0; s2 < 16; ++s2) l += part[t][s2];
        float m = l;
        #pragma unroll
        for (int off = 8; off; off >>= 1) m = fmaxf(m, __shfl_xor(m, off));
        float ex = __expf(l - m);
        float ssum = ex;
        #pragma unroll
        for (int off = 8; off; off >>= 1) ssum += __shfl_xor(ssum, off);
        out[g * 16 + t] = l - m - logf(ssum);
    }
}

// ---------------- launch ----------------

extern "C" void kernel_launch(void* const* d_in, const int* in_sizes, int n_in,
                              void* d_out, int out_size, void* d_ws, size_t ws_size,
                              hipStream_t stream) {
    const float* x      = (const float*)d_in[0];
    const int*   edge   = (const int*)d_in[1];
    const int*   batch  = (const int*)d_in[2];
    const float* ln_g0  = (const float*)d_in[3];
    const float* ln_b0  = (const float*)d_in[4];
    const float* W0     = (const float*)d_in[5];
    const float* att_s0 = (const float*)d_in[6];
    const float* att_d0 = (const float*)d_in[7];
    const float* bias0  = (const float*)d_in[8];
    const float* ln_g1  = (const float*)d_in[9];
    const float* ln_b1  = (const float*)d_in[10];
    const float* W1     = (const float*)d_in[11];
    const float* att_s1 = (const float*)d_in[12];
    const float* att_d1 = (const float*)d_in[13];
    const float* bias1  = (const float*)d_in[14];
    const float* ln_gr  = (const float*)d_in[15];
    const float* ln_br  = (const float*)d_in[16];
    const float* Wr     = (const float*)d_in[17];
    float* outp = (float*)d_out;

    const int N = N_NODES, E = N_EDGES;
    const int* src = edge;
    const int* dst = edge + E;
    const int NB = (N + 255) / 256;   // 196 scan blocks

    unsigned char* ws = (unsigned char*)d_ws;
    size_t off = 0;
    auto alloc = [&](size_t nbytes) {
        unsigned char* p = ws + off;
        off += (nbytes + 255) & ~(size_t)255;
        return (void*)p;
    };
    __hip_bfloat16* W0b   = (__hip_bfloat16*)alloc(256 * 512 * 2);
    __hip_bfloat16* W1b   = (__hip_bfloat16*)alloc(256 * 1024 * 2);
    __hip_bfloat16* h_bf  = (__hip_bfloat16*)alloc((size_t)N * 256 * 2);
    __hip_bfloat16* xmid  = (__hip_bfloat16*)alloc((size_t)N * 256 * 2);  // reused for layer-2 output
    float* as_    = (float*)alloc((size_t)N * 4 * 4);
    float* ad_    = (float*)alloc((size_t)N * 4 * 4);
    int*   rowptr = (int*)alloc((N + 1) * 4);
    int*   cursor = (int*)alloc(N * 4);
    int*   deg    = (int*)alloc(N * 4);
    int*   bsum   = (int*)alloc(NB * 4);
    int*   csr_src= (int*)alloc((size_t)(E + N) * 4);
    float* pooled = (float*)alloc(N_GRAPHS * 256 * 4);

    deg_init<<<(N + 255) / 256, 256, 0, stream>>>(deg, N);
    deg_count<<<(E + 255) / 256, 256, 0, stream>>>(dst, deg, E);
    convert_w_perm<<<(256 * 128 + 255) / 256, 256, 0, stream>>>(W0, W0b, 128, 2, 256 * 128);
    convert_w_perm<<<(256 * 256 + 255) / 256, 256, 0, stream>>>(W1, W1b, 256, 4, 256 * 256);
    scan_blocks<<<NB, 256, 0, stream>>>(deg, rowptr, bsum, N);
    scan_tops<<<1, 256, 0, stream>>>(bsum, NB);
    scan_apply<<<NB, 256, 0, stream>>>(bsum, rowptr, cursor, N, E + N);
    csr_fill<<<(E + N + 255) / 256, 256, 0, stream>>>(src, dst, cursor, csr_src, E, N);

    // layer 0
    fastkan_mfma<128, false><<<(N + 63) / 64, 256, 0, stream>>>(x, ln_g0, ln_b0, W0b,
                                                                att_s0, att_d0, h_bf, as_, ad_, N);
    gat_agg<<<N, 256, 0, stream>>>(rowptr, csr_src, as_, ad_, h_bf, bias0, xmid);

    // layer 1
    fastkan_mfma<256, true><<<(N + 63) / 64, 256, 0, stream>>>(xmid, ln_g1, ln_b1, W1b,
                                                               att_s1, att_d1, h_bf, as_, ad_, N);
    gat_agg<<<N, 256, 0, stream>>>(rowptr, csr_src, as_, ad_, h_bf, bias1, xmid);

    // pooling (batch sorted -> segmented streaming sum) + readout
    zero_f32<<<(N_GRAPHS * 256 + 255) / 256, 256, 0, stream>>>(pooled, N_GRAPHS * 256);
    pool_kernel<<<N_GRAPHS * 4, 256, 0, stream>>>(xmid, batch, pooled, N);
    readout_kernel<<<N_GRAPHS, 256, 0, stream>>>(pooled, ln_gr, ln_br, Wr, outp);
}

// Round 10
// 598.515 us; speedup vs baseline: 1.3898x; 1.0088x over previous
//
#include <hip/hip_runtime.h>
#include <hip/hip_bf16.h>

#define N_NODES 50000
#define N_EDGES 800000
#define F_IN 128
#define HC 256
#define HEADS 4
#define HID 64
#define N_GRAPHS 64
#define N_CLASSES 16

typedef __attribute__((ext_vector_type(8))) short bfrag;    // 8 bf16 (4 VGPRs)
typedef __attribute__((ext_vector_type(4))) float f32x4;    // MFMA accumulator

__device__ __forceinline__ float wave_sum(float v) {
    #pragma unroll
    for (int off = 32; off > 0; off >>= 1) v += __shfl_xor(v, off);
    return v;
}

__device__ __forceinline__ unsigned int pack_bf2(float a, float b) {
    unsigned int ua = __bfloat16_as_ushort(__float2bfloat16(a));
    unsigned int ub = __bfloat16_as_ushort(__float2bfloat16(b));
    return ua | (ub << 16);
}

__device__ __forceinline__ float bf_lo(unsigned int u) { return __uint_as_float(u << 16); }
__device__ __forceinline__ float bf_hi(unsigned int u) { return __uint_as_float(u & 0xffff0000u); }

// ---------------- small utility kernels ----------------

__global__ void zero_f32(float* __restrict__ p, int n) {
    int i = blockIdx.x * 256 + threadIdx.x;
    if (i < n) p[i] = 0.f;
}

__global__ void deg_init(int* __restrict__ deg, int n) {
    int i = blockIdx.x * 256 + threadIdx.x;
    if (i < n) deg[i] = 1;  // self-loop
}

__global__ void deg_count(const int* __restrict__ dst, int* __restrict__ deg, int E) {
    int e = blockIdx.x * 256 + threadIdx.x;
    if (e < E) atomicAdd(&deg[dst[e]], 1);
}

// ---- parallel 3-stage exclusive scan over deg[n] -> rowptr/cursor ----
__global__ __launch_bounds__(256) void scan_blocks(const int* __restrict__ deg,
                                                   int* __restrict__ rowptr,
                                                   int* __restrict__ blocksum, int n) {
    __shared__ int wsum[4];
    int i = blockIdx.x * 256 + threadIdx.x;
    int lane = threadIdx.x & 63, w = threadIdx.x >> 6;
    int v = (i < n) ? deg[i] : 0;
    int x = v;
    #pragma unroll
    for (int off = 1; off < 64; off <<= 1) {
        int y = __shfl_up(x, off);
        if (lane >= off) x += y;
    }
    if (lane == 63) wsum[w] = x;
    __syncthreads();
    int add = 0;
    #pragma unroll
    for (int k = 0; k < 4; ++k) add += (k < w) ? wsum[k] : 0;
    int incl = x + add;
    if (i < n) rowptr[i] = incl - v;             // exclusive, pre-offset
    if (threadIdx.x == 255) blocksum[blockIdx.x] = incl;  // block total
}

__global__ __launch_bounds__(256) void scan_tops(int* __restrict__ blocksum, int nb) {
    __shared__ int s[256];
    int t = threadIdx.x;
    int v = (t < nb) ? blocksum[t] : 0;
    s[t] = v;
    __syncthreads();
    for (int off = 1; off < 256; off <<= 1) {
        int u = (t >= off) ? s[t - off] : 0;
        __syncthreads();
        s[t] += u;
        __syncthreads();
    }
    if (t < nb) blocksum[t] = s[t] - v;          // exclusive offset
}

__global__ __launch_bounds__(256) void scan_apply(const int* __restrict__ blocksum,
                                                  int* __restrict__ rowptr,
                                                  int* __restrict__ cursor, int n, int total) {
    int i = blockIdx.x * 256 + threadIdx.x;
    if (i < n) {
        int v = rowptr[i] + blocksum[blockIdx.x];
        rowptr[i] = v; cursor[i] = v;
    }
    if (i == 0) rowptr[n] = total;
}

__global__ void csr_fill(const int* __restrict__ src, const int* __restrict__ dst,
                         int* __restrict__ cursor, int* __restrict__ csr_src, int E, int N) {
    int e = blockIdx.x * 256 + threadIdx.x;
    if (e >= E + N) return;
    int s, d;
    if (e < E) { s = src[e]; d = dst[e]; } else { s = d = e - E; }
    int pos = atomicAdd(&cursor[d], 1);
    csr_src[pos] = s;
}

// f32 -> bf16 weights with phase-interleaved K permutation:
// out k-group j (4 elems) = p*64 + l  <-  in k-group = NPH*l + p
__global__ void convert_w_perm(const float* __restrict__ W, __hip_bfloat16* __restrict__ Wb,
                               int KQ /* = K/4 */, int NPH, int total /* = 256*KQ */) {
    int idx = blockIdx.x * 256 + threadIdx.x;
    if (idx >= total) return;
    int o = idx / KQ, j = idx - o * KQ;
    int p = j >> 6, l = j & 63;
    int in4 = NPH * l + p;
    float4 v = *reinterpret_cast<const float4*>(W + (size_t)o * (KQ * 4) + in4 * 4);
    ushort4 u;
    u.x = __bfloat16_as_ushort(__float2bfloat16(v.x));
    u.y = __bfloat16_as_ushort(__float2bfloat16(v.y));
    u.z = __bfloat16_as_ushort(__float2bfloat16(v.z));
    u.w = __bfloat16_as_ushort(__float2bfloat16(v.w));
    *reinterpret_cast<ushort4*>(Wb + (size_t)o * (KQ * 4) + j * 4) = u;
}

// ---------------- FastKAN via MFMA ----------------
// 64 nodes/block, 256 threads (4 waves). Wave w owns output cols [64w,64w+64) = head w,
// rows mf*16+lc (mf=0..3) -> each B-fragment feeds 4 MFMAs.
// K split into NPH phases by dim interleave (32KB LDS slab); W pre-permuted to match.
// Output staged in LDS (reusing bas) then written fully coalesced (uint4 rows).
template <int IN, bool XBF>
__global__ __launch_bounds__(256, 4) void fastkan_mfma(
    const void* __restrict__ xin_v, const float* __restrict__ ln_g, const float* __restrict__ ln_b,
    const __hip_bfloat16* __restrict__ Wb, const float* __restrict__ att_s, const float* __restrict__ att_d,
    __hip_bfloat16* __restrict__ hout, float* __restrict__ as_out, float* __restrict__ ad_out, int nnodes)
{
    constexpr int K   = IN * 4;    // total K (bf16 elements)
    constexpr int DPL = IN / 64;   // dims per lane (2 or 4) == phase count NPH
    constexpr int NPH = DPL;
    __shared__ __align__(16) unsigned char bas[64 * 512];   // [64 rows][256 k] per phase; reused as out tile

    int t = threadIdx.x, lane = t & 63, w = t >> 6;
    int lc = lane & 15, lr = lane >> 4;
    int base = blockIdx.x * 64;

    // ln params for this lane's dims (contiguous DPL*lane .. +DPL-1)
    float lng[DPL], lnb[DPL];
    if constexpr (DPL == 4) {
        float4 g4 = *reinterpret_cast<const float4*>(ln_g + 4 * lane);
        float4 b4 = *reinterpret_cast<const float4*>(ln_b + 4 * lane);
        lng[0] = g4.x; lng[1] = g4.y; lng[2] = g4.z; lng[3] = g4.w;
        lnb[0] = b4.x; lnb[1] = b4.y; lnb[2] = b4.z; lnb[3] = b4.w;
    } else {
        float2 g2 = *reinterpret_cast<const float2*>(ln_g + 2 * lane);
        float2 b2 = *reinterpret_cast<const float2*>(ln_b + 2 * lane);
        lng[0] = g2.x; lng[1] = g2.y;
        lnb[0] = b2.x; lnb[1] = b2.y;
    }

    // ---- stats + normalize: wave w handles rows 16w..16w+15 ----
    unsigned int vk[16][DPL / 2];
    #pragma unroll
    for (int j = 0; j < 16; ++j) {
        int node = base + w * 16 + j;
        float xv[DPL];
        #pragma unroll
        for (int i = 0; i < DPL; ++i) xv[i] = 0.f;
        if (node < nnodes) {
            if constexpr (XBF) {
                const unsigned short* xs = (const unsigned short*)xin_v + (size_t)node * IN + DPL * lane;
                if constexpr (DPL == 4) {
                    uint2 u = *reinterpret_cast<const uint2*>(xs);
                    xv[0] = bf_lo(u.x); xv[1] = bf_hi(u.x);
                    xv[2] = bf_lo(u.y); xv[3] = bf_hi(u.y);
                } else {
                    unsigned int u = *reinterpret_cast<const unsigned int*>(xs);
                    xv[0] = bf_lo(u); xv[1] = bf_hi(u);
                }
            } else {
                const float* xr = (const float*)xin_v + (size_t)node * IN + DPL * lane;
                if constexpr (DPL == 2) {
                    float2 v2 = *reinterpret_cast<const float2*>(xr);
                    xv[0] = v2.x; xv[1] = v2.y;
                } else {
                    float4 v4 = *reinterpret_cast<const float4*>(xr);
                    xv[0] = v4.x; xv[1] = v4.y; xv[2] = v4.z; xv[3] = v4.w;
                }
            }
        }
        float s = 0.f, sq = 0.f;
        #pragma unroll
        for (int i = 0; i < DPL; ++i) { s += xv[i]; sq += xv[i] * xv[i]; }
        s = wave_sum(s); sq = wave_sum(sq);
        float mean = s * (1.f / IN);
        float var  = sq * (1.f / IN) - mean * mean;
        float rs = rsqrtf(var + 1e-5f);
        #pragma unroll
        for (int i = 0; i < DPL; i += 2) {
            float va = (xv[i]     - mean) * rs * lng[i]     + lnb[i];
            float vb = (xv[i + 1] - mean) * rs * lng[i + 1] + lnb[i + 1];
            vk[j][i / 2] = pack_bf2(va, vb);
        }
    }

    // phase-p basis write: row r, lane writes 4 RBF values (8B) of its dim i=p
    auto write_phase = [&](int p) {
        #pragma unroll
        for (int j = 0; j < 16; ++j) {
            int r = w * 16 + j;
            unsigned int pkd = vk[j][p >> 1];
            float v = (p & 1) ? bf_hi(pkd) : bf_lo(pkd);
            float t0 = (v + 2.f) * 0.75f;
            float t1 = (v + 2.f / 3.f) * 0.75f;
            float t2 = (v - 2.f / 3.f) * 0.75f;
            float t3 = (v - 2.f) * 0.75f;
            uint2 o;
            o.x = pack_bf2(__expf(-t0 * t0), __expf(-t1 * t1));
            o.y = pack_bf2(__expf(-t2 * t2), __expf(-t3 * t3));
            *reinterpret_cast<uint2*>(bas + r * 512 + ((lane * 8) ^ ((r & 7) << 4))) = o;
        }
    };

    write_phase(0);

    // ---- MFMA phases: acc[mf][nf], rows mf*16+lc, cols w*64+nf*16+lc ----
    f32x4 acc[4][4] = {};
    const __hip_bfloat16* wrow = Wb + (size_t)(w * 64 + lc) * K + lr * 8;

    #pragma unroll
    for (int p = 0; p < NPH; ++p) {
        __syncthreads();   // phase-p basis visible
        #pragma unroll
        for (int ks = 0; ks < 8; ++ks) {
            int poff = (ks * 64 + lr * 16) ^ ((lc & 7) << 4);
            bfrag a0 = *reinterpret_cast<const bfrag*>(bas + (0 * 16 + lc) * 512 + poff);
            bfrag a1 = *reinterpret_cast<const bfrag*>(bas + (1 * 16 + lc) * 512 + poff);
            bfrag a2 = *reinterpret_cast<const bfrag*>(bas + (2 * 16 + lc) * 512 + poff);
            bfrag a3 = *reinterpret_cast<const bfrag*>(bas + (3 * 16 + lc) * 512 + poff);
            #pragma unroll
            for (int nf = 0; nf < 4; ++nf) {
                bfrag b = *reinterpret_cast<const bfrag*>(wrow + (size_t)nf * 16 * K + p * 256 + ks * 32);
                acc[0][nf] = __builtin_amdgcn_mfma_f32_16x16x32_bf16(a0, b, acc[0][nf], 0, 0, 0);
                acc[1][nf] = __builtin_amdgcn_mfma_f32_16x16x32_bf16(a1, b, acc[1][nf], 0, 0, 0);
                acc[2][nf] = __builtin_amdgcn_mfma_f32_16x16x32_bf16(a2, b, acc[2][nf], 0, 0, 0);
                acc[3][nf] = __builtin_amdgcn_mfma_f32_16x16x32_bf16(a3, b, acc[3][nf], 0, 0, 0);
            }
        }
        if (p + 1 < NPH) {
            __syncthreads();   // all waves done reading phase p
            write_phase(p + 1);
        }
    }

    // ---- attention logits (register-only; C/D layout col=lane&15, row=(lane>>4)*4+reg) ----
    float asw[4], adw[4];
    #pragma unroll
    for (int nf = 0; nf < 4; ++nf) {
        asw[nf] = att_s[w * 64 + nf * 16 + lc];
        adw[nf] = att_d[w * 64 + nf * 16 + lc];
    }
    #pragma unroll
    for (int mf = 0; mf < 4; ++mf) {
        #pragma unroll
        for (int reg = 0; reg < 4; ++reg) {
            int node = base + mf * 16 + lr * 4 + reg;
            float ps = 0.f, pd = 0.f;
            #pragma unroll
            for (int nf = 0; nf < 4; ++nf) {
                float v = acc[mf][nf][reg];
                ps = fmaf(v, asw[nf], ps);
                pd = fmaf(v, adw[nf], pd);
            }
            #pragma unroll
            for (int off = 8; off; off >>= 1) {
                ps += __shfl_xor(ps, off);
                pd += __shfl_xor(pd, off);
            }
            if (node < nnodes && lc == 0) {
                as_out[node * 4 + w] = ps;
                ad_out[node * 4 + w] = pd;
            }
        }
    }

    // ---- stage C tile into LDS (bf16 [64 rows][256 cols]) ----
    __syncthreads();   // all waves done reading bas (last MFMA phase)
    #pragma unroll
    for (int mf = 0; mf < 4; ++mf) {
        #pragma unroll
        for (int reg = 0; reg < 4; ++reg) {
            int row = mf * 16 + lr * 4 + reg;
            #pragma unroll
            for (int nf = 0; nf < 4; ++nf) {
                *reinterpret_cast<unsigned short*>(bas + row * 512 + (w * 64 + nf * 16 + lc) * 2) =
                    (unsigned short)(__bfloat16_as_ushort(__float2bfloat16(acc[mf][nf][reg])));
            }
        }
    }
    __syncthreads();

    // ---- coalesced global write: wave w streams rows 16w..16w+15, 2 rows / iter ----
    #pragma unroll
    for (int it = 0; it < 8; ++it) {
        int r = w * 16 + it * 2 + (lane >> 5);
        int node = base + r;
        if (node < nnodes) {
            uint4 v = *reinterpret_cast<const uint4*>(bas + r * 512 + (lane & 31) * 16);
            *reinterpret_cast<uint4*>((unsigned char*)hout + (size_t)node * 512 + (lane & 31) * 16) = v;
        }
    }
}

// ---------------- fused GAT aggregation ----------------
// Block per dst node; 4 waves split the edge list (stride-4 interleave).
// Lane owns 4 columns (uint2 = 8B gather per edge). Partials combined in LDS.
__global__ __launch_bounds__(256) void gat_agg(
    const int* __restrict__ rowptr, const int* __restrict__ csr_src,
    const float* __restrict__ as_, const float* __restrict__ ad_,
    const __hip_bfloat16* __restrict__ h, const float* __restrict__ bias,
    __hip_bfloat16* __restrict__ out)
{
    __shared__ float accs[4][256];
    __shared__ float ses[4][4];
    int d = blockIdx.x, t = threadIdx.x, w = t >> 6, lane = t & 63;
    int head = lane >> 4;                 // cols lane*4..lane*4+3 are in head lane>>4
    int r0 = rowptr[d], r1 = rowptr[d + 1];
    float adv = ad_[d * 4 + head];
    const unsigned char* hb = (const unsigned char*)h;
    size_t loff = (size_t)lane * 8;

    float a0 = 0.f, a1 = 0.f, a2 = 0.f, a3 = 0.f, se = 0.f;
    int r = r0 + w;
    for (; r + 8 <= r1; r += 8) {
        int s0 = csr_src[r], s1 = csr_src[r + 4];
        float v0 = as_[s0 * 4 + head], v1 = as_[s1 * 4 + head];
        uint2 h0 = *reinterpret_cast<const uint2*>(hb + (size_t)s0 * 512 + loff);
        uint2 h1 = *reinterpret_cast<const uint2*>(hb + (size_t)s1 * 512 + loff);
        float e0 = v0 + adv; e0 = e0 > 0.f ? e0 : 0.2f * e0; e0 = __expf(e0);
        float e1 = v1 + adv; e1 = e1 > 0.f ? e1 : 0.2f * e1; e1 = __expf(e1);
        a0 = fmaf(e0, bf_lo(h0.x), a0); a1 = fmaf(e0, bf_hi(h0.x), a1);
        a2 = fmaf(e0, bf_lo(h0.y), a2); a3 = fmaf(e0, bf_hi(h0.y), a3);
        a0 = fmaf(e1, bf_lo(h1.x), a0); a1 = fmaf(e1, bf_hi(h1.x), a1);
        a2 = fmaf(e1, bf_lo(h1.y), a2); a3 = fmaf(e1, bf_hi(h1.y), a3);
        se += e0 + e1;
    }
    for (; r < r1; r += 4) {
        int s0 = csr_src[r];
        float v0 = as_[s0 * 4 + head];
        uint2 h0 = *reinterpret_cast<const uint2*>(hb + (size_t)s0 * 512 + loff);
        float e0 = v0 + adv; e0 = e0 > 0.f ? e0 : 0.2f * e0; e0 = __expf(e0);
        a0 = fmaf(e0, bf_lo(h0.x), a0); a1 = fmaf(e0, bf_hi(h0.x), a1);
        a2 = fmaf(e0, bf_lo(h0.y), a2); a3 = fmaf(e0, bf_hi(h0.y), a3);
        se += e0;
    }

    float4 av; av.x = a0; av.y = a1; av.z = a2; av.w = a3;
    *reinterpret_cast<float4*>(&accs[w][lane * 4]) = av;
    if ((lane & 15) == 0) ses[w][head] = se;
    __syncthreads();

    // combine: thread t owns column t
    float tot = accs[0][t] + accs[1][t] + accs[2][t] + accs[3][t];
    int hh = t >> 6;
    float sed = ses[0][hh] + ses[1][hh] + ses[2][hh] + ses[3][hh];
    float val = tot / sed + bias[t];
    val = val / (1.f + __expf(-val));  // silu
    out[(size_t)d * 256 + t] = __float2bfloat16(val);
}

// segment-sum pooling over sorted batch: block = (graph g, row-quarter q).
__global__ __launch_bounds__(256) void pool_kernel(
    const __hip_bfloat16* __restrict__ xo, const int* __restrict__ batch,
    float* __restrict__ pooled, int N)
{
    int g = blockIdx.x >> 2, q = blockIdx.x & 3, t = threadIdx.x;
    int lo = 0, hi = N;
    while (lo < hi) { int m = (lo + hi) >> 1; if (batch[m] < g) lo = m + 1; else hi = m; }
    int start = lo;
    hi = N;
    while (lo < hi) { int m = (lo + hi) >> 1; if (batch[m] <= g) lo = m + 1; else hi = m; }
    int end = lo;
    const unsigned short* xu = (const unsigned short*)xo;
    float acc = 0.f;
    for (int r = start + q; r < end; r += 4)
        acc += bf_lo(xu[(size_t)r * 256 + t]);
    atomicAdd(&pooled[g * 256 + t], acc);
}

// readout: LN -> RBF -> [16] logits -> log_softmax, one block per graph
__global__ __launch_bounds__(256) void readout_kernel(
    const float* __restrict__ pooled, const float* __restrict__ ln_g, const float* __restrict__ ln_b,
    const float* __restrict__ Wr, float* __restrict__ out)
{
    __shared__ __align__(16) float bas[1024];
    __shared__ float red[8];
    __shared__ float part[16][17];
    int t = threadIdx.x, lane = t & 63, w = t >> 6;
    int g = blockIdx.x;
    float val = pooled[g * 256 + t];
    float s = wave_sum(val), sq = wave_sum(val * val);
    if (lane == 0) { red[w] = s; red[4 + w] = sq; }
    __syncthreads();
    float stot = red[0] + red[1] + red[2] + red[3];
    float sqtot = red[4] + red[5] + red[6] + red[7];
    float mean = stot * (1.f / 256), var = sqtot * (1.f / 256) - mean * mean;
    float rs = rsqrtf(var + 1e-5f);
    float v = (val - mean) * rs * ln_g[t] + ln_b[t];
    float t0 = (v + 2.f) * 0.75f;
    float t1 = (v + 2.f / 3.f) * 0.75f;
    float t2 = (v - 2.f / 3.f) * 0.75f;
    float t3 = (v - 2.f) * 0.75f;
    float4 e4;
    e4.x = __expf(-t0 * t0); e4.y = __expf(-t1 * t1);
    e4.z = __expf(-t2 * t2); e4.w = __expf(-t3 * t3);
    reinterpret_cast<float4*>(bas)[t] = e4;
    __syncthreads();
    int o = t & 15, slice = t >> 4;
    float p = 0.f;
    const float* wrow = Wr + o * 1024 + slice * 64;
    const float* brow = bas + slice * 64;
    #pragma unroll 8
    for (int kk = 0; kk < 64; ++kk) p = fmaf(brow[kk], wrow[kk], p);
    part[o][slice] = p;
    __syncthreads();
    if (t < 16) {
        float l = 0.f;
        #pragma unroll
        for (int s2 = 0; s2 < 16; ++s2) l += part[t][s2];
        float m = l;
        #pragma unroll
        for (int off = 8; off; off >>= 1) m = fmaxf(m, __shfl_xor(m, off));
        float ex = __expf(l - m);
        float ssum = ex;
        #pragma unroll
        for (int off = 8; off; off >>= 1) ssum += __shfl_xor(ssum, off);
        out[g * 16 + t] = l - m - logf(ssum);
    }
}

// ---------------- launch ----------------

extern "C" void kernel_launch(void* const* d_in, const int* in_sizes, int n_in,
                              void* d_out, int out_size, void* d_ws, size_t ws_size,
                              hipStream_t stream) {
    const float* x      = (const float*)d_in[0];
    const int*   edge   = (const int*)d_in[1];
    const int*   batch  = (const int*)d_in[2];
    const float* ln_g0  = (const float*)d_in[3];
    const float* ln_b0  = (const float*)d_in[4];
    const float* W0     = (const float*)d_in[5];
    const float* att_s0 = (const float*)d_in[6];
    const float* att_d0 = (const float*)d_in[7];
    const float* bias0  = (const float*)d_in[8];
    const float* ln_g1  = (const float*)d_in[9];
    const float* ln_b1  = (const float*)d_in[10];
    const float* W1     = (const float*)d_in[11];
    const float* att_s1 = (const float*)d_in[12];
    const float* att_d1 = (const float*)d_in[13];
    const float* bias1  = (const float*)d_in[14];
    const float* ln_gr  = (const float*)d_in[15];
    const float* ln_br  = (const float*)d_in[16];
    const float* Wr     = (const float*)d_in[17];
    float* outp = (float*)d_out;

    const int N = N_NODES, E = N_EDGES;
    const int* src = edge;
    const int* dst = edge + E;
    const int NB = (N + 255) / 256;   // 196 scan blocks

    unsigned char* ws = (unsigned char*)d_ws;
    size_t off = 0;
    auto alloc = [&](size_t nbytes) {
        unsigned char* p = ws + off;
        off += (nbytes + 255) & ~(size_t)255;
        return (void*)p;
    };
    __hip_bfloat16* W0b   = (__hip_bfloat16*)alloc(256 * 512 * 2);
    __hip_bfloat16* W1b   = (__hip_bfloat16*)alloc(256 * 1024 * 2);
    __hip_bfloat16* h_bf  = (__hip_bfloat16*)alloc((size_t)N * 256 * 2);
    __hip_bfloat16* xmid  = (__hip_bfloat16*)alloc((size_t)N * 256 * 2);  // reused for layer-2 output
    float* as_    = (float*)alloc((size_t)N * 4 * 4);
    float* ad_    = (float*)alloc((size_t)N * 4 * 4);
    int*   rowptr = (int*)alloc((N + 1) * 4);
    int*   cursor = (int*)alloc(N * 4);
    int*   deg    = (int*)alloc(N * 4);
    int*   bsum   = (int*)alloc(NB * 4);
    int*   csr_src= (int*)alloc((size_t)(E + N) * 4);
    float* pooled = (float*)alloc(N_GRAPHS * 256 * 4);

    deg_init<<<(N + 255) / 256, 256, 0, stream>>>(deg, N);
    deg_count<<<(E + 255) / 256, 256, 0, stream>>>(dst, deg, E);
    convert_w_perm<<<(256 * 128 + 255) / 256, 256, 0, stream>>>(W0, W0b, 128, 2, 256 * 128);
    convert_w_perm<<<(256 * 256 + 255) / 256, 256, 0, stream>>>(W1, W1b, 256, 4, 256 * 256);
    scan_blocks<<<NB, 256, 0, stream>>>(deg, rowptr, bsum, N);
    scan_tops<<<1, 256, 0, stream>>>(bsum, NB);
    scan_apply<<<NB, 256, 0, stream>>>(bsum, rowptr, cursor, N, E + N);
    csr_fill<<<(E + N + 255) / 256, 256, 0, stream>>>(src, dst, cursor, csr_src, E, N);

    // layer 0
    fastkan_mfma<128, false><<<(N + 63) / 64, 256, 0, stream>>>(x, ln_g0, ln_b0, W0b,
                                                                att_s0, att_d0, h_bf, as_, ad_, N);
    gat_agg<<<N, 256, 0, stream>>>(rowptr, csr_src, as_, ad_, h_bf, bias0, xmid);

    // layer 1
    fastkan_mfma<256, true><<<(N + 63) / 64, 256, 0, stream>>>(xmid, ln_g1, ln_b1, W1b,
                                                               att_s1, att_d1, h_bf, as_, ad_, N);
    gat_agg<<<N, 256, 0, stream>>>(rowptr, csr_src, as_, ad_, h_bf, bias1, xmid);

    // pooling (batch sorted -> segmented streaming sum) + readout
    zero_f32<<<(N_GRAPHS * 256 + 255) / 256, 256, 0, stream>>>(pooled, N_GRAPHS * 256);
    pool_kernel<<<N_GRAPHS * 4, 256, 0, stream>>>(xmid, batch, pooled, N);
    readout_kernel<<<N_GRAPHS, 256, 0, stream>>>(pooled, ln_gr, ln_br, Wr, outp);
}